// Round 4
// baseline (653.353 us; speedup 1.0000x reference)
//
#include <hip/hip_runtime.h>

typedef unsigned short u16;
typedef unsigned int u32;
typedef unsigned long long u64;

#define T_ 4
#define N_ 20000
#define E_ 640000
#define DIN 256
#define DOUT 128
#define NT (T_*N_)          // 80000
#define TE (T_*E_)          // 2560000
#define SLOPE 0.22916666666666666f

// coarse binning geometry: 125 buckets of 160 nodes per timestep
#define NB 125
#define BNODES 160
#define CAP 5632            // mean 5120, sigma ~72 -> 14 sigma headroom
#define NBTOT (T_*NB)       // 500

// k_scatter composite sort: primary key = src band of 2048 nodes, secondary = dstLocal
#define SGRAN 11
#define NSB 10              // ceil(20000 / 2048)
#define NBIN (NSB*BNODES)   // 1600
#define NBIN_PAD 2048

typedef __attribute__((ext_vector_type(8))) short short8;
typedef __attribute__((ext_vector_type(4))) float f32x4;

__device__ __forceinline__ float blo(u32 u) { return __uint_as_float(u << 16); }
__device__ __forceinline__ float bhi(u32 u) { return __uint_as_float(u & 0xFFFF0000u); }
__device__ __forceinline__ u16 f2bf(float f) {
    u32 u = __float_as_uint(f);
    return (u16)((u + 0x7FFFu + ((u >> 16) & 1u)) >> 16);
}
__device__ __forceinline__ u32 fkey(float f) {
    u32 u = __float_as_uint(f);
    return (u & 0x80000000u) ? ~u : (u | 0x80000000u);
}
__device__ __forceinline__ float fkeyinv(u32 k) {
    u32 u = (k & 0x80000000u) ? (k ^ 0x80000000u) : ~k;
    return __uint_as_float(u);
}

// ---------------- transpose+pack the 6 GRU weight matrices (f32 -> bf16 pairs) ------
__global__ void k_transpose(const float* Wz, const float* Uz, const float* Wr, const float* Ur,
                            const float* Wh, const float* Uh, u32* Tp) {
    int bid = blockIdx.x;
    int m = bid >> 7, b = bid & 127;
    int idx = b * 256 + threadIdx.x;      // 0..32767
    int d2 = idx & 127, i = idx >> 7;     // coalesced f32 pair reads
    const float* src;
    switch (m) {
        case 0: src = Wz; break;
        case 1: src = Uz; break;
        case 2: src = Wr; break;
        case 3: src = Ur; break;
        case 4: src = Wh; break;
        default: src = Uh; break;
    }
    float lo = src[i * 256 + 2 * d2];
    float hi = src[i * 256 + 2 * d2 + 1];
    Tp[m * 32768 + d2 * 256 + i] = (u32)f2bf(lo) | ((u32)f2bf(hi) << 16);
}

// ---------------- scores: (x.p)/||p|| + mask, plus x -> bf16 conversion ----------------
__global__ __launch_bounds__(256) void k_scores(const float* x, const float* p, const float* mask,
                                                float* scores, u16* xb16) {
    __shared__ float pl[256];
    __shared__ float s_invn;
    int tid = threadIdx.x;
    pl[tid] = p[tid];
    __syncthreads();
    if (tid < 64) {
        float v = pl[tid] * pl[tid] + pl[tid + 64] * pl[tid + 64] +
                  pl[tid + 128] * pl[tid + 128] + pl[tid + 192] * pl[tid + 192];
        for (int o = 32; o > 0; o >>= 1) v += __shfl_xor(v, o);
        if (tid == 0) s_invn = 1.0f / sqrtf(v);
    }
    __syncthreads();
    int wid = tid >> 6, lane = tid & 63;
    for (int it = 0; it < 4; ++it) {
        int node = blockIdx.x * 16 + wid * 4 + it;   // 5000*16 == 80000
        const float* row = x + (size_t)node * DIN + lane * 4;
        float4 u = *(const float4*)row;
        float d = u.x * pl[lane * 4 + 0] + u.y * pl[lane * 4 + 1] +
                  u.z * pl[lane * 4 + 2] + u.w * pl[lane * 4 + 3];
        u32 p0 = (u32)f2bf(u.x) | ((u32)f2bf(u.y) << 16);
        u32 p1 = (u32)f2bf(u.z) | ((u32)f2bf(u.w) << 16);
        *(uint2*)(xb16 + (size_t)node * DIN + lane * 4) = make_uint2(p0, p1);
        for (int o = 32; o > 0; o >>= 1) d += __shfl_xor(d, o);
        if (lane == 0) scores[node] = d * s_invn + mask[node];
    }
}

// ---------------- phase 1: LDS-staged coarse binning ----------------
// Pack: bits [0,17) = t*N+src, [17,25) = dstLocal (0..159), [25,32) = bucket (0..124)
__global__ __launch_bounds__(256) void k_bin(const int* ei, const float* ew,
                                             int* gcur, uint2* binned) {
    int blk = blockIdx.x;                // 0..999
    int t = blk / 250, ci = blk - t * 250;
    int ebase = ci * 2560;
    int tid = threadIdx.x;
    __shared__ u32 hist[128], sc[128], gbase[128];
    __shared__ uint2 stage[2560];
    if (tid < 128) hist[tid] = 0;
    __syncthreads();
    u32 px[10]; u32 pw[10]; u16 rk[10];
#pragma unroll
    for (int k = 0; k < 10; ++k) {
        int e = ebase + tid + k * 256;                  // < E_ exactly
        int dst = ei[t * (2 * E_) + e];
        int src = ei[t * (2 * E_) + E_ + e];
        float w = ew[t * E_ + e];
        int b = dst / BNODES;                           // 0..124
        int dl = dst - b * BNODES;                      // 0..159
        px[k] = (u32)(t * N_ + src) | ((u32)dl << 17) | ((u32)b << 25);
        pw[k] = __float_as_uint(w);
        rk[k] = (u16)atomicAdd(&hist[b], 1u);
    }
    __syncthreads();
    // inclusive scan of hist (125 live, padded to 128)
    if (tid < 128) sc[tid] = hist[tid];
    __syncthreads();
    for (int o = 1; o < 128; o <<= 1) {
        u32 v = 0;
        if (tid < 128) { v = sc[tid]; if (tid >= o) v += sc[tid - o]; }
        __syncthreads();
        if (tid < 128) sc[tid] = v;
        __syncthreads();
    }
    // reserve contiguous global runs (one atomic per bucket per block)
    if (tid < NB) gbase[tid] = (u32)atomicAdd(&gcur[t * NB + tid], (int)hist[tid]);
    // stage into bucket-sorted LDS order: slot = exclusiveStart(b) + rank
#pragma unroll
    for (int k = 0; k < 10; ++k) {
        int b = px[k] >> 25;
        u32 slot = (sc[b] - hist[b]) + rk[k];
        stage[slot] = make_uint2(px[k], pw[k]);
    }
    __syncthreads();
    // flush: consecutive slots -> consecutive global addresses within each bucket run
    for (int s = tid; s < 2560; s += 256) {
        uint2 v = stage[s];
        int b = v.x >> 25;
        u32 local = gbase[b] + ((u32)s - (sc[b] - hist[b]));
        if (local < CAP)
            binned[(size_t)(t * NB + b) * CAP + local] = v;
    }
}

// ---------------- phase 2: in-place per-bucket counting sort by (src-band, node) -------
// src-band-major order phase-locks the y-gather across all resident blocks -> L2-fit.
// Pads (w=0, src=last row, dl spread over 0..159) are sorted into band 9's tail.
// Emits bandoff[bucket][band][wave]: start of (band b, dl in [w*20,(w+1)*20)).
__global__ __launch_bounds__(512) void k_scatter(const int* gcur, uint2* binned, int* bandoff) {
    int bg = blockIdx.x;                 // 0..499
    int t = bg / NB;
    uint2* bucket = binned + (size_t)bg * CAP;
    int cnt = gcur[bg]; if (cnt > CAP) cnt = CAP;
    int tid = threadIdx.x;
    int tbase = t * N_;
    __shared__ u32 nhist[NBIN_PAD];
    __shared__ u32 binstart[NBIN_PAD];
    __shared__ u32 wsum[8];
    for (int i = tid; i < NBIN_PAD; i += 512) nhist[i] = 0;
    __syncthreads();
    u32 vx[11]; u32 vw[11]; u16 r_[11]; u16 bn_[11];
#pragma unroll
    for (int k = 0; k < 11; ++k) {       // 11*512 = 5632 = CAP
        int e = tid + k * 512;
        uint2 v;
        if (e < cnt) {
            v = bucket[e];
        } else {
            // synthetic pad: zero weight, reads a real row, dl spread for wave balance
            v = make_uint2(((u32)(e % BNODES) << 17) | (u32)(tbase + N_ - 1), 0u);
        }
        vx[k] = v.x; vw[k] = v.y;
        int dl = (v.x >> 17) & 255;
        int s = (int)(v.x & 0x1FFFFu) - tbase;          // 0..19999
        int bin = (s >> SGRAN) * BNODES + dl;           // (band, dl) -> 0..1599
        bn_[k] = (u16)bin;
        r_[k] = (u16)atomicAdd(&nhist[bin], 1u);
    }
    __syncthreads();
    // exclusive scan over 2048 bins: thread sums 4, then scan 512 thread-sums
    u32 loc1, loc2, loc3, tsum;
    {
        int b0 = tid * 4;
        u32 a = nhist[b0], b = nhist[b0 + 1], c = nhist[b0 + 2], d = nhist[b0 + 3];
        loc1 = a; loc2 = a + b; loc3 = a + b + c; tsum = a + b + c + d;
    }
    int lane = tid & 63, wv = tid >> 6;
    u32 xsc = tsum;
    for (int o = 1; o < 64; o <<= 1) { u32 yv = __shfl_up(xsc, o); if (lane >= o) xsc += yv; }
    if (lane == 63) wsum[wv] = xsc;
    __syncthreads();
    u32 wpre = 0;
    for (int wq = 0; wq < wv; ++wq) wpre += wsum[wq];
    u32 tpre = wpre + xsc - tsum;
    {
        int b0 = tid * 4;
        binstart[b0] = tpre;
        binstart[b0 + 1] = tpre + loc1;
        binstart[b0 + 2] = tpre + loc2;
        binstart[b0 + 3] = tpre + loc3;
    }
    __syncthreads();
    if (tid < 80)   // band b = tid>>3, wave w = tid&7 -> bin b*160 + w*20
        bandoff[bg * 80 + tid] = (int)binstart[(tid >> 3) * BNODES + (tid & 7) * 20];
#pragma unroll
    for (int k = 0; k < 11; ++k) {
        u32 pos = binstart[bn_[k]] + r_[k];             // exact permutation of 0..CAP-1
        bucket[pos] = make_uint2(vx[k] & 0x1FFFFFFu, vw[k]);   // keep (dl, src)
    }
}

// ---------------- top-128 (radix select, exact jax order) + xtT build ----------------
__global__ __launch_bounds__(1024) void k_topk(const float* scores, const float* x, float* xtT) {
    int t = blockIdx.x;
    int tid = threadIdx.x;   // 0..1023
    const float* sc = scores + t * N_;
    __shared__ u32 hist[256];
    __shared__ u32 sh_dig, sh_need;
    __shared__ u64 sel[256];
    __shared__ u32 selCount;
    __shared__ u32 idxl[128];
    __shared__ float tvl[128];

    u32 kreg[20];
#pragma unroll
    for (int p = 0; p < 20; ++p) {
        int i = tid + p * 1024;
        kreg[p] = (i < N_) ? fkey(sc[i]) : 0u;
    }

    u32 pref = 0;
    u32 need = 128;
    for (int pass = 0; pass < 4; ++pass) {
        int shift = 24 - 8 * pass;
        if (tid < 256) hist[tid] = 0;
        __syncthreads();
#pragma unroll
        for (int p = 0; p < 20; ++p) {
            int i = tid + p * 1024;
            u32 k = kreg[p];
            bool ok = (i < N_) && ((pass == 0) || ((k >> (shift + 8)) == pref));
            if (ok) atomicAdd(&hist[(k >> shift) & 255u], 1u);
        }
        __syncthreads();
        if (tid < 64) {
            int l = tid;
            u32 s = hist[4 * l] + hist[4 * l + 1] + hist[4 * l + 2] + hist[4 * l + 3];
            u32 S = s;
            for (int o = 1; o < 64; o <<= 1) {
                u32 y = __shfl_down(S, o);
                if (l + o < 64) S += y;
            }
            u64 m = __ballot(S >= need);
            int L = 63 - __builtin_clzll(m);
            if (l == L) {
                u32 Snext = S - s;
                u32 r = 0;
                for (int dd = 3; dd >= 0; --dd) {
                    u32 hb = hist[4 * L + dd];
                    r += hb;
                    if (Snext + r >= need) {
                        sh_dig = (u32)(4 * L + dd);
                        sh_need = need - (Snext + r - hb);
                        break;
                    }
                }
            }
        }
        __syncthreads();
        pref = (pref << 8) | sh_dig;
        need = sh_need;
        __syncthreads();
    }
    if (tid == 0) selCount = 0;
    __syncthreads();
    u32 theta = pref;
#pragma unroll
    for (int p = 0; p < 20; ++p) {
        int i = tid + p * 1024;
        u32 k = kreg[p];
        if (i < N_ && k >= theta) {
            u32 pos = atomicAdd(&selCount, 1u);
            if (pos < 256) sel[pos] = (((u64)(k ^ 0xFFFFFFFFu)) << 32) | (u32)i;
        }
    }
    __syncthreads();
    u32 c = selCount;
    if (c > 256) c = 256;
    if (tid < 256 && (u32)tid >= c) sel[tid] = 0xFFFFFFFFFFFFFFFFull;
    __syncthreads();
    // bitonic ascending sort: key = (~fkey)<<32 | idx  -> value desc, idx asc
    for (int k2 = 2; k2 <= 256; k2 <<= 1) {
        for (int jj = k2 >> 1; jj > 0; jj >>= 1) {
            if (tid < 256) {
                int i = tid, ixj = i ^ jj;
                if (ixj > i) {
                    u64 A = sel[i], B = sel[ixj];
                    bool asc = ((i & k2) == 0);
                    bool sw = asc ? (A > B) : (A < B);
                    if (sw) { sel[i] = B; sel[ixj] = A; }
                }
            }
            __syncthreads();
        }
    }
    if (tid < 128) {
        u64 v = sel[tid];
        u32 k = ((u32)(v >> 32)) ^ 0xFFFFFFFFu;
        idxl[tid] = (u32)(v & 0xFFFFFFFFu);
        tvl[tid] = tanhf(fkeyinv(k));
    }
    __syncthreads();
    float* xt_t = xtT + t * (DIN * DOUT);
    const float* xb = x + (size_t)t * N_ * DIN;
    for (int e2 = tid; e2 < DIN * DOUT; e2 += 1024) {
        int j = e2 >> 8, d = e2 & 255;
        xt_t[e2] = xb[(size_t)idxl[j] * DIN + d] * tvl[j];
    }
}

// ---------------- fused matrix-GRU, all 4 timesteps in one launch -------------------
// Column recurrence is independent across columns: W[:,j] at t+1 depends only on
// W[:,j] at t. Carry W in registers; no global W ping-pong, no inter-t launches.
__global__ __launch_bounds__(256) void k_gru(const float* xtT, const float* W0, const u32* Tp,
                                             const float* bz, const float* br, const float* bh,
                                             u16* WnT) {
    int j0 = blockIdx.x;          // 0..63
    int j1 = j0 + 64;
    int i = threadIdx.x;          // 0..255
    __shared__ float sxt[2][256], sW[2][256], srw[2][256];
    const u32* WzT = Tp;
    const u32* UzT = Tp + 32768;
    const u32* WrT = Tp + 65536;
    const u32* UrT = Tp + 98304;
    const u32* WhT = Tp + 131072;
    const u32* UhT = Tp + 163840;
    float wv0 = W0[i * 128 + j0];
    float wv1 = W0[i * 128 + j1];
    float azb0 = bz[i * 128 + j0], azb1 = bz[i * 128 + j1];
    float arb0 = br[i * 128 + j0], arb1 = br[i * 128 + j1];
    float ahb0 = bh[i * 128 + j0], ahb1 = bh[i * 128 + j1];
    for (int t = 0; t < T_; ++t) {
        __syncthreads();          // previous iteration's LDS reads complete
        sxt[0][i] = xtT[t * 32768 + j0 * 256 + i];
        sxt[1][i] = xtT[t * 32768 + j1 * 256 + i];
        sW[0][i] = wv0;
        sW[1][i] = wv1;
        __syncthreads();
        float az0 = azb0, az1 = azb1, ar0 = arb0, ar1 = arb1;
#pragma unroll 4
        for (int d2 = 0; d2 < 128; ++d2) {
            float x00 = sxt[0][2 * d2], x01 = sxt[0][2 * d2 + 1];
            float x10 = sxt[1][2 * d2], x11 = sxt[1][2 * d2 + 1];
            float w00 = sW[0][2 * d2], w01 = sW[0][2 * d2 + 1];
            float w10 = sW[1][2 * d2], w11 = sW[1][2 * d2 + 1];
            u32 a = WzT[d2 * 256 + i], b = UzT[d2 * 256 + i];
            u32 cc = WrT[d2 * 256 + i], dd = UrT[d2 * 256 + i];
            az0 += blo(a) * x00 + bhi(a) * x01 + blo(b) * w00 + bhi(b) * w01;
            az1 += blo(a) * x10 + bhi(a) * x11 + blo(b) * w10 + bhi(b) * w11;
            ar0 += blo(cc) * x00 + bhi(cc) * x01 + blo(dd) * w00 + bhi(dd) * w01;
            ar1 += blo(cc) * x10 + bhi(cc) * x11 + blo(dd) * w10 + bhi(dd) * w11;
        }
        float z0 = 1.0f / (1.0f + expf(-az0));
        float z1 = 1.0f / (1.0f + expf(-az1));
        float r0 = 1.0f / (1.0f + expf(-ar0));
        float r1 = 1.0f / (1.0f + expf(-ar1));
        srw[0][i] = r0 * wv0;
        srw[1][i] = r1 * wv1;
        __syncthreads();
        float ah0 = ahb0, ah1 = ahb1;
#pragma unroll 4
        for (int d2 = 0; d2 < 128; ++d2) {
            float x00 = sxt[0][2 * d2], x01 = sxt[0][2 * d2 + 1];
            float x10 = sxt[1][2 * d2], x11 = sxt[1][2 * d2 + 1];
            float r00 = srw[0][2 * d2], r01 = srw[0][2 * d2 + 1];
            float r10 = srw[1][2 * d2], r11 = srw[1][2 * d2 + 1];
            u32 a = WhT[d2 * 256 + i], b = UhT[d2 * 256 + i];
            ah0 += blo(a) * x00 + bhi(a) * x01 + blo(b) * r00 + bhi(b) * r01;
            ah1 += blo(a) * x10 + bhi(a) * x11 + blo(b) * r10 + bhi(b) * r11;
        }
        float h0 = tanhf(ah0), h1 = tanhf(ah1);
        float wn0 = (1.0f - z0) * wv0 + z0 * h0;
        float wn1 = (1.0f - z1) * wv1 + z1 * h1;
        WnT[t * 32768 + j0 * 256 + i] = f2bf(wn0);
        WnT[t * 32768 + j1 * 256 + i] = f2bf(wn1);
        wv0 = wn0;
        wv1 = wn1;
    }
}

// ---------------- y = x_bf16 @ Wn (MFMA bf16), batched over t ----------------
__global__ __launch_bounds__(128) void k_gemm(const u16* xb16, const u16* WnT, u16* y) {
    int t = blockIdx.y;
    const u16* xb = xb16 + (size_t)t * N_ * DIN;
    const u16* Bt = WnT + t * (DIN * DOUT);
    u16* yb = y + (size_t)t * N_ * DOUT;
    int wid = threadIdx.x >> 6, lane = threadIdx.x & 63;
    int quad = lane >> 4, lm = lane & 15;
    int rowBase = blockIdx.x * 64 + wid * 32;
    f32x4 acc[2][8];
#pragma unroll
    for (int mi = 0; mi < 2; ++mi)
#pragma unroll
        for (int ni = 0; ni < 8; ++ni) acc[mi][ni] = (f32x4){0.f, 0.f, 0.f, 0.f};
    size_t aoff[2];
#pragma unroll
    for (int mi = 0; mi < 2; ++mi) {
        int r = rowBase + mi * 16 + lm;
        if (r > N_ - 1) r = N_ - 1;
        aoff[mi] = (size_t)r * DIN + quad * 8;
    }
    const u16* bbase = Bt + lm * 256 + quad * 8;
    for (int kk = 0; kk < 256; kk += 32) {
        short8 a0 = *(const short8*)(xb + aoff[0] + kk);
        short8 a1 = *(const short8*)(xb + aoff[1] + kk);
#pragma unroll
        for (int ni = 0; ni < 8; ++ni) {
            short8 b = *(const short8*)(bbase + ni * 4096 + kk);
            acc[0][ni] = __builtin_amdgcn_mfma_f32_16x16x32_bf16(a0, b, acc[0][ni], 0, 0, 0);
            acc[1][ni] = __builtin_amdgcn_mfma_f32_16x16x32_bf16(a1, b, acc[1][ni], 0, 0, 0);
        }
    }
#pragma unroll
    for (int mi = 0; mi < 2; ++mi)
#pragma unroll
        for (int ni = 0; ni < 8; ++ni)
#pragma unroll
            for (int r = 0; r < 4; ++r) {
                int row = rowBase + mi * 16 + quad * 4 + r;
                if (row < N_) yb[(size_t)row * DOUT + ni * 16 + lm] = f2bf(acc[mi][ni][r]);
            }
}

// ---------------- bucket-resident aggregation (replaces CSR gather) ----------------
// One block per (t, bucket): 160 dst rows in 80KB LDS f32, 2 blocks/CU, all 500
// co-resident. 8 waves: wave w exclusively owns rows [w*20,(w+1)*20) (dims 2l,2l+1
// per lane) -> non-atomic LDS. Edges walked src-band-major; all blocks advance
// through the same y_t bands in lockstep -> per-XCD L2 footprint ~1.5MB < 4MB.
// XCD swizzle: bid&7 = xcd, t = xcd>>1 -> each XCD touches only one timestep's y.
__global__ __launch_bounds__(512) void k_agg(const uint2* binned, const int* bandoff,
                                             const u16* y, float* out) {
    int bid = blockIdx.x;                 // 0..511 (12 dead)
    int xcd = bid & 7;
    int t = xcd >> 1;
    int bl = ((bid >> 3) << 1) + (xcd & 1);
    if (bl >= NB) return;
    int bg = t * NB + bl;
    const uint2* bucket = binned + (size_t)bg * CAP;
    const int* boff = bandoff + bg * 80;
    int w = threadIdx.x >> 6, l = threadIdx.x & 63;
    __shared__ float acc[8][20][128];     // 80 KB
#pragma unroll
    for (int r = 0; r < 20; ++r)
        *(float2*)&acc[w][r][2 * l] = make_float2(0.f, 0.f);
    // no __syncthreads needed anywhere: waves touch only their own LDS section
    const u16* yl = y + 2 * l;
    int curdl = -1;
    float a0 = 0.f, a1 = 0.f;
    for (int b = 0; b < NSB; ++b) {
        int idx = b * 8 + w;
        int e = boff[idx];
        int eend = (idx < 79) ? boff[idx + 1] : CAP;
        for (; e < eend; ++e) {
            uint2 m = bucket[e];          // wave-uniform 8B load (broadcast)
            int dl = (int)((m.x >> 17) & 255u);
            if (dl != curdl) {
                if (curdl >= 0) {
                    float* rp = &acc[w][curdl - w * 20][2 * l];
                    rp[0] += a0; rp[1] += a1;
                }
                a0 = 0.f; a1 = 0.f; curdl = dl;
            }
            float wt = __uint_as_float(m.y);
            u32 yv = *(const u32*)(yl + (size_t)(m.x & 0x1FFFFu) * DOUT);  // 256B/wave
            a0 += wt * blo(yv);
            a1 += wt * bhi(yv);
        }
    }
    if (curdl >= 0) {
        float* rp = &acc[w][curdl - w * 20][2 * l];
        rp[0] += a0; rp[1] += a1;
    }
    // epilogue: RReLU + coalesced store of the wave's 20 rows
    int gbase = t * N_ + bl * BNODES + w * 20;
#pragma unroll
    for (int r = 0; r < 20; ++r) {
        float v0 = acc[w][r][2 * l], v1 = acc[w][r][2 * l + 1];
        v0 = (v0 >= 0.f) ? v0 : SLOPE * v0;
        v1 = (v1 >= 0.f) ? v1 : SLOPE * v1;
        *(float2*)(out + (size_t)(gbase + r) * DOUT + 2 * l) = make_float2(v0, v1);
    }
}

extern "C" void kernel_launch(void* const* d_in, const int* in_sizes, int n_in,
                              void* d_out, int out_size, void* d_ws, size_t ws_size,
                              hipStream_t stream) {
    const float* x = (const float*)d_in[0];
    const int* ei = (const int*)d_in[1];
    const float* ew = (const float*)d_in[2];
    const float* mask = (const float*)d_in[3];
    const float* p = (const float*)d_in[4];
    const float* Wz = (const float*)d_in[5];
    const float* Uz = (const float*)d_in[6];
    const float* bz = (const float*)d_in[7];
    const float* Wr = (const float*)d_in[8];
    const float* Ur = (const float*)d_in[9];
    const float* br = (const float*)d_in[10];
    const float* Wh = (const float*)d_in[11];
    const float* Uh = (const float*)d_in[12];
    const float* bh = (const float*)d_in[13];
    const float* W0 = (const float*)d_in[14];
    float* out = (float*)d_out;

    char* w = (char*)d_ws;
    u16* xb16 = (u16*)w;        w += (size_t)NT * DIN * 2;        // 40,960,000
    float* scores = (float*)w;  w += 320256;                      // NT f32
    float* xtT = (float*)w;     w += 4 * 32768 * 4;               // [t][128][256] f32
    u16* WnT = (u16*)w;         w += 4 * 32768 * 2;               // [t][128][256] bf16
    u32* Tp = (u32*)w;          w += 6 * 32768 * 4;               // packed transposed weights
    u16* y = (u16*)w;           w += (size_t)NT * DOUT * 2;       // [t][N][128] bf16
    uint2* binned = (uint2*)w;  w += (size_t)NBTOT * CAP * 8;     // bucketed edges (in-place sort)
    int* gcur = (int*)w;        w += 2048;                        // 500 bucket cursors
    int* bandoff = (int*)w;     w += NBTOT * 80 * 4;              // [bucket][band][wave] starts

    hipMemsetAsync(gcur, 0, 2048, stream);

    k_transpose<<<768, 256, 0, stream>>>(Wz, Uz, Wr, Ur, Wh, Uh, Tp);
    k_scores<<<5000, 256, 0, stream>>>(x, p, mask, scores, xb16);
    k_bin<<<1000, 256, 0, stream>>>(ei, ew, gcur, binned);
    k_scatter<<<NBTOT, 512, 0, stream>>>(gcur, binned, bandoff);
    k_topk<<<4, 1024, 0, stream>>>(scores, x, xtT);
    k_gru<<<64, 256, 0, stream>>>(xtT, W0, Tp, bz, br, bh, WnT);
    k_gemm<<<dim3(313, 4), 128, 0, stream>>>(xb16, WnT, y);
    k_agg<<<512, 512, 0, stream>>>(binned, bandoff, y, out);
}

// Round 6
// 511.262 us; speedup vs baseline: 1.2779x; 1.2779x over previous
//
#include <hip/hip_runtime.h>

typedef unsigned short u16;
typedef unsigned int u32;
typedef unsigned long long u64;

#define T_ 4
#define N_ 20000
#define E_ 640000
#define DIN 256
#define DOUT 128
#define NT (T_*N_)          // 80000
#define TE (T_*E_)          // 2560000
#define SLOPE 0.22916666666666666f

// coarse binning geometry: 125 buckets of 160 nodes per timestep
#define NB 125
#define BNODES 160
#define CAP 5632            // mean 5120, sigma ~72 -> 14 sigma headroom
#define NBTOT (T_*NB)       // 500

// k_scatter composite sort: primary key = src band of 2048 nodes, secondary = dstLocal
#define SGRAN 11
#define NSB 10              // ceil(20000 / 2048)
#define NBIN (NSB*BNODES)   // 1600
#define NBIN_PAD 2048
#define BOSTRIDE 328        // 321 range boundaries per bucket, padded

typedef __attribute__((ext_vector_type(8))) short short8;
typedef __attribute__((ext_vector_type(4))) float f32x4;

__device__ __forceinline__ float blo(u32 u) { return __uint_as_float(u << 16); }
__device__ __forceinline__ float bhi(u32 u) { return __uint_as_float(u & 0xFFFF0000u); }
__device__ __forceinline__ u16 f2bf(float f) {
    u32 u = __float_as_uint(f);
    return (u16)((u + 0x7FFFu + ((u >> 16) & 1u)) >> 16);
}
__device__ __forceinline__ u32 fkey(float f) {
    u32 u = __float_as_uint(f);
    return (u & 0x80000000u) ? ~u : (u | 0x80000000u);
}
__device__ __forceinline__ float fkeyinv(u32 k) {
    u32 u = (k & 0x80000000u) ? (k ^ 0x80000000u) : ~k;
    return __uint_as_float(u);
}

// ---------------- transpose+pack the 6 GRU weight matrices (f32 -> bf16 pairs) ------
__global__ void k_transpose(const float* Wz, const float* Uz, const float* Wr, const float* Ur,
                            const float* Wh, const float* Uh, u32* Tp) {
    int bid = blockIdx.x;
    int m = bid >> 7, b = bid & 127;
    int idx = b * 256 + threadIdx.x;      // 0..32767
    int d2 = idx & 127, i = idx >> 7;     // coalesced f32 pair reads
    const float* src;
    switch (m) {
        case 0: src = Wz; break;
        case 1: src = Uz; break;
        case 2: src = Wr; break;
        case 3: src = Ur; break;
        case 4: src = Wh; break;
        default: src = Uh; break;
    }
    float lo = src[i * 256 + 2 * d2];
    float hi = src[i * 256 + 2 * d2 + 1];
    Tp[m * 32768 + d2 * 256 + i] = (u32)f2bf(lo) | ((u32)f2bf(hi) << 16);
}

// ---------------- scores: (x.p)/||p|| + mask, plus x -> bf16 conversion ----------------
__global__ __launch_bounds__(256) void k_scores(const float* x, const float* p, const float* mask,
                                                float* scores, u16* xb16) {
    __shared__ float pl[256];
    __shared__ float s_invn;
    int tid = threadIdx.x;
    pl[tid] = p[tid];
    __syncthreads();
    if (tid < 64) {
        float v = pl[tid] * pl[tid] + pl[tid + 64] * pl[tid + 64] +
                  pl[tid + 128] * pl[tid + 128] + pl[tid + 192] * pl[tid + 192];
        for (int o = 32; o > 0; o >>= 1) v += __shfl_xor(v, o);
        if (tid == 0) s_invn = 1.0f / sqrtf(v);
    }
    __syncthreads();
    int wid = tid >> 6, lane = tid & 63;
    for (int it = 0; it < 4; ++it) {
        int node = blockIdx.x * 16 + wid * 4 + it;   // 5000*16 == 80000
        const float* row = x + (size_t)node * DIN + lane * 4;
        float4 u = *(const float4*)row;
        float d = u.x * pl[lane * 4 + 0] + u.y * pl[lane * 4 + 1] +
                  u.z * pl[lane * 4 + 2] + u.w * pl[lane * 4 + 3];
        u32 p0 = (u32)f2bf(u.x) | ((u32)f2bf(u.y) << 16);
        u32 p1 = (u32)f2bf(u.z) | ((u32)f2bf(u.w) << 16);
        *(uint2*)(xb16 + (size_t)node * DIN + lane * 4) = make_uint2(p0, p1);
        for (int o = 32; o > 0; o >>= 1) d += __shfl_xor(d, o);
        if (lane == 0) scores[node] = d * s_invn + mask[node];
    }
}

// ---------------- phase 1: LDS-staged coarse binning ----------------
// Pack: bits [0,17) = t*N+src, [17,25) = dstLocal (0..159), [25,32) = bucket (0..124)
__global__ __launch_bounds__(256) void k_bin(const int* ei, const float* ew,
                                             int* gcur, uint2* binned) {
    int blk = blockIdx.x;                // 0..999
    int t = blk / 250, ci = blk - t * 250;
    int ebase = ci * 2560;
    int tid = threadIdx.x;
    __shared__ u32 hist[128], sc[128], gbase[128];
    __shared__ uint2 stage[2560];
    if (tid < 128) hist[tid] = 0;
    __syncthreads();
    u32 px[10]; u32 pw[10]; u16 rk[10];
#pragma unroll
    for (int k = 0; k < 10; ++k) {
        int e = ebase + tid + k * 256;                  // < E_ exactly
        int dst = ei[t * (2 * E_) + e];
        int src = ei[t * (2 * E_) + E_ + e];
        float w = ew[t * E_ + e];
        int b = dst / BNODES;                           // 0..124
        int dl = dst - b * BNODES;                      // 0..159
        px[k] = (u32)(t * N_ + src) | ((u32)dl << 17) | ((u32)b << 25);
        pw[k] = __float_as_uint(w);
        rk[k] = (u16)atomicAdd(&hist[b], 1u);
    }
    __syncthreads();
    // inclusive scan of hist (125 live, padded to 128)
    if (tid < 128) sc[tid] = hist[tid];
    __syncthreads();
    for (int o = 1; o < 128; o <<= 1) {
        u32 v = 0;
        if (tid < 128) { v = sc[tid]; if (tid >= o) v += sc[tid - o]; }
        __syncthreads();
        if (tid < 128) sc[tid] = v;
        __syncthreads();
    }
    // reserve contiguous global runs (one atomic per bucket per block)
    if (tid < NB) gbase[tid] = (u32)atomicAdd(&gcur[t * NB + tid], (int)hist[tid]);
    // stage into bucket-sorted LDS order: slot = exclusiveStart(b) + rank
#pragma unroll
    for (int k = 0; k < 10; ++k) {
        int b = px[k] >> 25;
        u32 slot = (sc[b] - hist[b]) + rk[k];
        stage[slot] = make_uint2(px[k], pw[k]);
    }
    __syncthreads();
    // flush: consecutive slots -> consecutive global addresses within each bucket run
    for (int s = tid; s < 2560; s += 256) {
        uint2 v = stage[s];
        int b = v.x >> 25;
        u32 local = gbase[b] + ((u32)s - (sc[b] - hist[b]));
        if (local < CAP)
            binned[(size_t)(t * NB + b) * CAP + local] = v;
    }
}

// ---------------- phase 2: in-place per-bucket counting sort by (src-band, node) -------
// src-band-major order phase-locks the y-gather across all resident blocks -> L2-fit.
// Pads (w=0, src=last row, dl spread over 0..159) sort into band 9's tail.
// Emits 321 boundaries per bucket: bandoff[bg][i] = binstart[i*5] (i<320), CAP (i=320).
// Range i covers (band b = i>>5, dl in [(i&31)*5, (i&31)*5+5)); quarter Q of k_agg
// walks ranges i = b*32 + Q for b = 0..9.
__global__ __launch_bounds__(512) void k_scatter(const int* gcur, uint2* binned, int* bandoff) {
    int bg = blockIdx.x;                 // 0..499
    int t = bg / NB;
    uint2* bucket = binned + (size_t)bg * CAP;
    int cnt = gcur[bg]; if (cnt > CAP) cnt = CAP;
    int tid = threadIdx.x;
    int tbase = t * N_;
    __shared__ u32 nhist[NBIN_PAD];
    __shared__ u32 binstart[NBIN_PAD];
    __shared__ u32 wsum[8];
    for (int i = tid; i < NBIN_PAD; i += 512) nhist[i] = 0;
    __syncthreads();
    u32 vx[11]; u32 vw[11]; u16 r_[11]; u16 bn_[11];
#pragma unroll
    for (int k = 0; k < 11; ++k) {       // 11*512 = 5632 = CAP
        int e = tid + k * 512;
        uint2 v;
        if (e < cnt) {
            v = bucket[e];
        } else {
            // synthetic pad: zero weight, reads a real row, dl spread for balance
            v = make_uint2(((u32)(e % BNODES) << 17) | (u32)(tbase + N_ - 1), 0u);
        }
        vx[k] = v.x; vw[k] = v.y;
        int dl = (v.x >> 17) & 255;
        int s = (int)(v.x & 0x1FFFFu) - tbase;          // 0..19999
        int bin = (s >> SGRAN) * BNODES + dl;           // (band, dl) -> 0..1599
        bn_[k] = (u16)bin;
        r_[k] = (u16)atomicAdd(&nhist[bin], 1u);
    }
    __syncthreads();
    // exclusive scan over 2048 bins: thread sums 4, then scan 512 thread-sums
    u32 loc1, loc2, loc3, tsum;
    {
        int b0 = tid * 4;
        u32 a = nhist[b0], b = nhist[b0 + 1], c = nhist[b0 + 2], d = nhist[b0 + 3];
        loc1 = a; loc2 = a + b; loc3 = a + b + c; tsum = a + b + c + d;
    }
    int lane = tid & 63, wv = tid >> 6;
    u32 xsc = tsum;
    for (int o = 1; o < 64; o <<= 1) { u32 yv = __shfl_up(xsc, o); if (lane >= o) xsc += yv; }
    if (lane == 63) wsum[wv] = xsc;
    __syncthreads();
    u32 wpre = 0;
    for (int wq = 0; wq < wv; ++wq) wpre += wsum[wq];
    u32 tpre = wpre + xsc - tsum;
    {
        int b0 = tid * 4;
        binstart[b0] = tpre;
        binstart[b0 + 1] = tpre + loc1;
        binstart[b0 + 2] = tpre + loc2;
        binstart[b0 + 3] = tpre + loc3;
    }
    __syncthreads();
    if (tid < 321) {
        int v = (tid < 320) ? (int)binstart[tid * 5] : CAP;
        bandoff[bg * BOSTRIDE + tid] = v;
    }
#pragma unroll
    for (int k = 0; k < 11; ++k) {
        u32 pos = binstart[bn_[k]] + r_[k];             // exact permutation of 0..CAP-1
        bucket[pos] = make_uint2(vx[k] & 0x1FFFFFFu, vw[k]);   // keep (dl, src)
    }
}

// ---------------- top-128 (radix select, exact jax order) + xtT build ----------------
__global__ __launch_bounds__(1024) void k_topk(const float* scores, const float* x, float* xtT) {
    int t = blockIdx.x;
    int tid = threadIdx.x;   // 0..1023
    const float* sc = scores + t * N_;
    __shared__ u32 hist[256];
    __shared__ u32 sh_dig, sh_need;
    __shared__ u64 sel[256];
    __shared__ u32 selCount;
    __shared__ u32 idxl[128];
    __shared__ float tvl[128];

    u32 kreg[20];
#pragma unroll
    for (int p = 0; p < 20; ++p) {
        int i = tid + p * 1024;
        kreg[p] = (i < N_) ? fkey(sc[i]) : 0u;
    }

    u32 pref = 0;
    u32 need = 128;
    for (int pass = 0; pass < 4; ++pass) {
        int shift = 24 - 8 * pass;
        if (tid < 256) hist[tid] = 0;
        __syncthreads();
#pragma unroll
        for (int p = 0; p < 20; ++p) {
            int i = tid + p * 1024;
            u32 k = kreg[p];
            bool ok = (i < N_) && ((pass == 0) || ((k >> (shift + 8)) == pref));
            if (ok) atomicAdd(&hist[(k >> shift) & 255u], 1u);
        }
        __syncthreads();
        if (tid < 64) {
            int l = tid;
            u32 s = hist[4 * l] + hist[4 * l + 1] + hist[4 * l + 2] + hist[4 * l + 3];
            u32 S = s;
            for (int o = 1; o < 64; o <<= 1) {
                u32 y = __shfl_down(S, o);
                if (l + o < 64) S += y;
            }
            u64 m = __ballot(S >= need);
            int L = 63 - __builtin_clzll(m);
            if (l == L) {
                u32 Snext = S - s;
                u32 r = 0;
                for (int dd = 3; dd >= 0; --dd) {
                    u32 hb = hist[4 * L + dd];
                    r += hb;
                    if (Snext + r >= need) {
                        sh_dig = (u32)(4 * L + dd);
                        sh_need = need - (Snext + r - hb);
                        break;
                    }
                }
            }
        }
        __syncthreads();
        pref = (pref << 8) | sh_dig;
        need = sh_need;
        __syncthreads();
    }
    if (tid == 0) selCount = 0;
    __syncthreads();
    u32 theta = pref;
#pragma unroll
    for (int p = 0; p < 20; ++p) {
        int i = tid + p * 1024;
        u32 k = kreg[p];
        if (i < N_ && k >= theta) {
            u32 pos = atomicAdd(&selCount, 1u);
            if (pos < 256) sel[pos] = (((u64)(k ^ 0xFFFFFFFFu)) << 32) | (u32)i;
        }
    }
    __syncthreads();
    u32 c = selCount;
    if (c > 256) c = 256;
    if (tid < 256 && (u32)tid >= c) sel[tid] = 0xFFFFFFFFFFFFFFFFull;
    __syncthreads();
    // bitonic ascending sort: key = (~fkey)<<32 | idx  -> value desc, idx asc
    for (int k2 = 2; k2 <= 256; k2 <<= 1) {
        for (int jj = k2 >> 1; jj > 0; jj >>= 1) {
            if (tid < 256) {
                int i = tid, ixj = i ^ jj;
                if (ixj > i) {
                    u64 A = sel[i], B = sel[ixj];
                    bool asc = ((i & k2) == 0);
                    bool sw = asc ? (A > B) : (A < B);
                    if (sw) { sel[i] = B; sel[ixj] = A; }
                }
            }
            __syncthreads();
        }
    }
    if (tid < 128) {
        u64 v = sel[tid];
        u32 k = ((u32)(v >> 32)) ^ 0xFFFFFFFFu;
        idxl[tid] = (u32)(v & 0xFFFFFFFFu);
        tvl[tid] = tanhf(fkeyinv(k));
    }
    __syncthreads();
    float* xt_t = xtT + t * (DIN * DOUT);
    const float* xb = x + (size_t)t * N_ * DIN;
    for (int e2 = tid; e2 < DIN * DOUT; e2 += 1024) {
        int j = e2 >> 8, d = e2 & 255;
        xt_t[e2] = xb[(size_t)idxl[j] * DIN + d] * tvl[j];
    }
}

// ---------------- fused matrix-GRU, all 4 timesteps in one launch -------------------
__global__ __launch_bounds__(256) void k_gru(const float* xtT, const float* W0, const u32* Tp,
                                             const float* bz, const float* br, const float* bh,
                                             u16* WnT) {
    int j0 = blockIdx.x;          // 0..63
    int j1 = j0 + 64;
    int i = threadIdx.x;          // 0..255
    __shared__ float sxt[2][256], sW[2][256], srw[2][256];
    const u32* WzT = Tp;
    const u32* UzT = Tp + 32768;
    const u32* WrT = Tp + 65536;
    const u32* UrT = Tp + 98304;
    const u32* WhT = Tp + 131072;
    const u32* UhT = Tp + 163840;
    float wv0 = W0[i * 128 + j0];
    float wv1 = W0[i * 128 + j1];
    float azb0 = bz[i * 128 + j0], azb1 = bz[i * 128 + j1];
    float arb0 = br[i * 128 + j0], arb1 = br[i * 128 + j1];
    float ahb0 = bh[i * 128 + j0], ahb1 = bh[i * 128 + j1];
    for (int t = 0; t < T_; ++t) {
        __syncthreads();          // previous iteration's LDS reads complete
        sxt[0][i] = xtT[t * 32768 + j0 * 256 + i];
        sxt[1][i] = xtT[t * 32768 + j1 * 256 + i];
        sW[0][i] = wv0;
        sW[1][i] = wv1;
        __syncthreads();
        float az0 = azb0, az1 = azb1, ar0 = arb0, ar1 = arb1;
#pragma unroll 4
        for (int d2 = 0; d2 < 128; ++d2) {
            float x00 = sxt[0][2 * d2], x01 = sxt[0][2 * d2 + 1];
            float x10 = sxt[1][2 * d2], x11 = sxt[1][2 * d2 + 1];
            float w00 = sW[0][2 * d2], w01 = sW[0][2 * d2 + 1];
            float w10 = sW[1][2 * d2], w11 = sW[1][2 * d2 + 1];
            u32 a = WzT[d2 * 256 + i], b = UzT[d2 * 256 + i];
            u32 cc = WrT[d2 * 256 + i], dd = UrT[d2 * 256 + i];
            az0 += blo(a) * x00 + bhi(a) * x01 + blo(b) * w00 + bhi(b) * w01;
            az1 += blo(a) * x10 + bhi(a) * x11 + blo(b) * w10 + bhi(b) * w11;
            ar0 += blo(cc) * x00 + bhi(cc) * x01 + blo(dd) * w00 + bhi(dd) * w01;
            ar1 += blo(cc) * x10 + bhi(cc) * x11 + blo(dd) * w10 + bhi(dd) * w11;
        }
        float z0 = 1.0f / (1.0f + expf(-az0));
        float z1 = 1.0f / (1.0f + expf(-az1));
        float r0 = 1.0f / (1.0f + expf(-ar0));
        float r1 = 1.0f / (1.0f + expf(-ar1));
        srw[0][i] = r0 * wv0;
        srw[1][i] = r1 * wv1;
        __syncthreads();
        float ah0 = ahb0, ah1 = ahb1;
#pragma unroll 4
        for (int d2 = 0; d2 < 128; ++d2) {
            float x00 = sxt[0][2 * d2], x01 = sxt[0][2 * d2 + 1];
            float x10 = sxt[1][2 * d2], x11 = sxt[1][2 * d2 + 1];
            float r00 = srw[0][2 * d2], r01 = srw[0][2 * d2 + 1];
            float r10 = srw[1][2 * d2], r11 = srw[1][2 * d2 + 1];
            u32 a = WhT[d2 * 256 + i], b = UhT[d2 * 256 + i];
            ah0 += blo(a) * x00 + bhi(a) * x01 + blo(b) * r00 + bhi(b) * r01;
            ah1 += blo(a) * x10 + bhi(a) * x11 + blo(b) * r10 + bhi(b) * r11;
        }
        float h0 = tanhf(ah0), h1 = tanhf(ah1);
        float wn0 = (1.0f - z0) * wv0 + z0 * h0;
        float wn1 = (1.0f - z1) * wv1 + z1 * h1;
        WnT[t * 32768 + j0 * 256 + i] = f2bf(wn0);
        WnT[t * 32768 + j1 * 256 + i] = f2bf(wn1);
        wv0 = wn0;
        wv1 = wn1;
    }
}

// ---------------- y = x_bf16 @ Wn (MFMA bf16), batched over t ----------------
__global__ __launch_bounds__(128) void k_gemm(const u16* xb16, const u16* WnT, u16* y) {
    int t = blockIdx.y;
    const u16* xb = xb16 + (size_t)t * N_ * DIN;
    const u16* Bt = WnT + t * (DIN * DOUT);
    u16* yb = y + (size_t)t * N_ * DOUT;
    int wid = threadIdx.x >> 6, lane = threadIdx.x & 63;
    int quad = lane >> 4, lm = lane & 15;
    int rowBase = blockIdx.x * 64 + wid * 32;
    f32x4 acc[2][8];
#pragma unroll
    for (int mi = 0; mi < 2; ++mi)
#pragma unroll
        for (int ni = 0; ni < 8; ++ni) acc[mi][ni] = (f32x4){0.f, 0.f, 0.f, 0.f};
    size_t aoff[2];
#pragma unroll
    for (int mi = 0; mi < 2; ++mi) {
        int r = rowBase + mi * 16 + lm;
        if (r > N_ - 1) r = N_ - 1;
        aoff[mi] = (size_t)r * DIN + quad * 8;
    }
    const u16* bbase = Bt + lm * 256 + quad * 8;
    for (int kk = 0; kk < 256; kk += 32) {
        short8 a0 = *(const short8*)(xb + aoff[0] + kk);
        short8 a1 = *(const short8*)(xb + aoff[1] + kk);
#pragma unroll
        for (int ni = 0; ni < 8; ++ni) {
            short8 b = *(const short8*)(bbase + ni * 4096 + kk);
            acc[0][ni] = __builtin_amdgcn_mfma_f32_16x16x32_bf16(a0, b, acc[0][ni], 0, 0, 0);
            acc[1][ni] = __builtin_amdgcn_mfma_f32_16x16x32_bf16(a1, b, acc[1][ni], 0, 0, 0);
        }
    }
#pragma unroll
    for (int mi = 0; mi < 2; ++mi)
#pragma unroll
        for (int ni = 0; ni < 8; ++ni)
#pragma unroll
            for (int r = 0; r < 4; ++r) {
                int row = rowBase + mi * 16 + quad * 4 + r;
                if (row < N_) yb[(size_t)row * DOUT + ni * 16 + lm] = f2bf(acc[mi][ni][r]);
            }
}

// ---------------- bucket-resident aggregation, quarter-parallel ----------------
// One block per (t, bucket): 160 dst rows in 80KB LDS f32, 2 blocks/CU, all 500
// co-resident. 32 quarters (16 lanes each): quarter Q = w*4+q owns dl in
// [Q*5, Q*5+5) -> exclusive LDS rows, no atomics, no barriers. Each quarter walks
// its (band, dl-chunk) ranges in band order -> all quarters chip-wide sweep src
// bands in lockstep (per-XCD y footprint ~1 band = 0.5MB << 4MB L2; R4-proven).
// Per edge: 16 lanes x uint4 = full 256B y row; run-accumulate 8 f32/lane in regs,
// flush 2x float4 LDS RMW on dl change (~3.5-edge runs). 4 edges in flight/wave.
__global__ __launch_bounds__(512, 4) void k_agg(const uint2* binned, const int* bandoff,
                                                const u16* y, float* out) {
    int bid = blockIdx.x;                 // 0..511 (12 dead)
    int xcd = bid & 7;
    int t = xcd >> 1;
    int bl = ((bid >> 3) << 1) + (xcd & 1);
    if (bl >= NB) return;
    int bg = t * NB + bl;
    const uint2* bucket = binned + (size_t)bg * CAP;
    const int* bo = bandoff + bg * BOSTRIDE;
    int w = threadIdx.x >> 6, lane = threadIdx.x & 63;
    int q = lane >> 4, lq = lane & 15;
    int Q = (w << 2) | q;                 // 0..31
    __shared__ float acc[BNODES][DOUT];   // 80 KB
#pragma unroll
    for (int r = 0; r < 20; ++r)
        *(float2*)&acc[w * 20 + r][2 * lane] = make_float2(0.f, 0.f);
    const u16* yq = y + lq * 8;
    int b = 0;
    int e = bo[Q];
    int eend = bo[Q + 1];
    int curdl = -1;
    float a0 = 0.f, a1 = 0.f, a2 = 0.f, a3 = 0.f, a4 = 0.f, a5 = 0.f, a6 = 0.f, a7 = 0.f;
    for (;;) {
        if (e >= eend) {
            bool done = false;
            do {
                ++b;
                if (b >= NSB) { done = true; break; }
                e = bo[b * 32 + Q];
                eend = bo[b * 32 + Q + 1];
            } while (e >= eend);
            if (done) break;
        }
        uint2 m = bucket[e]; ++e;         // quarter-uniform 8B load (broadcast)
        int dl = (int)((m.x >> 17) & 255u);
        if (dl != curdl) {
            if (curdl >= 0) {
                float4* rp = (float4*)&acc[curdl][lq * 8];
                float4 r0 = rp[0], r1 = rp[1];
                r0.x += a0; r0.y += a1; r0.z += a2; r0.w += a3;
                r1.x += a4; r1.y += a5; r1.z += a6; r1.w += a7;
                rp[0] = r0; rp[1] = r1;
            }
            a0 = a1 = a2 = a3 = a4 = a5 = a6 = a7 = 0.f;
            curdl = dl;
        }
        float wt = __uint_as_float(m.y);
        uint4 v = *(const uint4*)(yq + (size_t)(m.x & 0x1FFFFu) * DOUT);  // 256B/quarter
        a0 += wt * blo(v.x); a1 += wt * bhi(v.x);
        a2 += wt * blo(v.y); a3 += wt * bhi(v.y);
        a4 += wt * blo(v.z); a5 += wt * bhi(v.z);
        a6 += wt * blo(v.w); a7 += wt * bhi(v.w);
    }
    if (curdl >= 0) {
        float4* rp = (float4*)&acc[curdl][lq * 8];
        float4 r0 = rp[0], r1 = rp[1];
        r0.x += a0; r0.y += a1; r0.z += a2; r0.w += a3;
        r1.x += a4; r1.y += a5; r1.z += a6; r1.w += a7;
        rp[0] = r0; rp[1] = r1;
    }
    // epilogue: RReLU + coalesced store of the wave's own 20 rows (same-wave order)
    int gbase = t * N_ + bl * BNODES + w * 20;
#pragma unroll
    for (int r = 0; r < 20; ++r) {
        float v0 = acc[w * 20 + r][2 * lane], v1 = acc[w * 20 + r][2 * lane + 1];
        v0 = (v0 >= 0.f) ? v0 : SLOPE * v0;
        v1 = (v1 >= 0.f) ? v1 : SLOPE * v1;
        *(float2*)(out + (size_t)(gbase + r) * DOUT + 2 * lane) = make_float2(v0, v1);
    }
}

extern "C" void kernel_launch(void* const* d_in, const int* in_sizes, int n_in,
                              void* d_out, int out_size, void* d_ws, size_t ws_size,
                              hipStream_t stream) {
    const float* x = (const float*)d_in[0];
    const int* ei = (const int*)d_in[1];
    const float* ew = (const float*)d_in[2];
    const float* mask = (const float*)d_in[3];
    const float* p = (const float*)d_in[4];
    const float* Wz = (const float*)d_in[5];
    const float* Uz = (const float*)d_in[6];
    const float* bz = (const float*)d_in[7];
    const float* Wr = (const float*)d_in[8];
    const float* Ur = (const float*)d_in[9];
    const float* br = (const float*)d_in[10];
    const float* Wh = (const float*)d_in[11];
    const float* Uh = (const float*)d_in[12];
    const float* bh = (const float*)d_in[13];
    const float* W0 = (const float*)d_in[14];
    float* out = (float*)d_out;

    char* w = (char*)d_ws;
    u16* xb16 = (u16*)w;        w += (size_t)NT * DIN * 2;        // 40,960,000
    float* scores = (float*)w;  w += 320256;                      // NT f32
    float* xtT = (float*)w;     w += 4 * 32768 * 4;               // [t][128][256] f32
    u16* WnT = (u16*)w;         w += 4 * 32768 * 2;               // [t][128][256] bf16
    u32* Tp = (u32*)w;          w += 6 * 32768 * 4;               // packed transposed weights
    u16* y = (u16*)w;           w += (size_t)NT * DOUT * 2;       // [t][N][128] bf16
    uint2* binned = (uint2*)w;  w += (size_t)NBTOT * CAP * 8;     // bucketed edges (in-place sort)
    int* gcur = (int*)w;        w += 2048;                        // 500 bucket cursors
    int* bandoff = (int*)w;     w += NBTOT * BOSTRIDE * 4;        // [bucket][321 boundaries]

    hipMemsetAsync(gcur, 0, 2048, stream);

    k_transpose<<<768, 256, 0, stream>>>(Wz, Uz, Wr, Ur, Wh, Uh, Tp);
    k_scores<<<5000, 256, 0, stream>>>(x, p, mask, scores, xb16);
    k_bin<<<1000, 256, 0, stream>>>(ei, ew, gcur, binned);
    k_scatter<<<NBTOT, 512, 0, stream>>>(gcur, binned, bandoff);
    k_topk<<<4, 1024, 0, stream>>>(scores, x, xtT);
    k_gru<<<64, 256, 0, stream>>>(xtT, W0, Tp, bz, br, bh, WnT);
    k_gemm<<<dim3(313, 4), 128, 0, stream>>>(xb16, WnT, y);
    k_agg<<<512, 512, 0, stream>>>(binned, bandoff, y, out);
}

// Round 7
// 431.009 us; speedup vs baseline: 1.5159x; 1.1862x over previous
//
#include <hip/hip_runtime.h>

typedef unsigned short u16;
typedef unsigned int u32;
typedef unsigned long long u64;

#define T_ 4
#define N_ 20000
#define E_ 640000
#define DIN 256
#define DOUT 128
#define NT (T_*N_)          // 80000
#define TE (T_*E_)          // 2560000
#define SLOPE 0.22916666666666666f

// coarse binning geometry: 125 buckets of 160 nodes per timestep
#define NB 125
#define BNODES 160
#define CAP 5632            // mean 5120, sigma ~72 -> 14 sigma headroom
#define NBTOT (T_*NB)       // 500

// k_scatter composite sort key: (quarter = dl/5, src band, dl%5)
// -> each k_agg quarter owns ONE contiguous run, internally src-band-major
#define SGRAN 11
#define NSB 10              // ceil(20000 / 2048)
#define NBIN (32*NSB*5)     // 1600
#define NBIN_PAD 2048
#define BOSTRIDE 40         // 33 boundaries per bucket, padded

typedef __attribute__((ext_vector_type(8))) short short8;
typedef __attribute__((ext_vector_type(4))) float f32x4;

__device__ __forceinline__ float blo(u32 u) { return __uint_as_float(u << 16); }
__device__ __forceinline__ float bhi(u32 u) { return __uint_as_float(u & 0xFFFF0000u); }
__device__ __forceinline__ u16 f2bf(float f) {
    u32 u = __float_as_uint(f);
    return (u16)((u + 0x7FFFu + ((u >> 16) & 1u)) >> 16);
}
__device__ __forceinline__ u32 fkey(float f) {
    u32 u = __float_as_uint(f);
    return (u & 0x80000000u) ? ~u : (u | 0x80000000u);
}
__device__ __forceinline__ float fkeyinv(u32 k) {
    u32 u = (k & 0x80000000u) ? (k ^ 0x80000000u) : ~k;
    return __uint_as_float(u);
}

// ---------------- transpose+pack the 6 GRU weight matrices (f32 -> bf16 pairs) ------
__global__ void k_transpose(const float* Wz, const float* Uz, const float* Wr, const float* Ur,
                            const float* Wh, const float* Uh, u32* Tp) {
    int bid = blockIdx.x;
    int m = bid >> 7, b = bid & 127;
    int idx = b * 256 + threadIdx.x;      // 0..32767
    int d2 = idx & 127, i = idx >> 7;     // coalesced f32 pair reads
    const float* src;
    switch (m) {
        case 0: src = Wz; break;
        case 1: src = Uz; break;
        case 2: src = Wr; break;
        case 3: src = Ur; break;
        case 4: src = Wh; break;
        default: src = Uh; break;
    }
    float lo = src[i * 256 + 2 * d2];
    float hi = src[i * 256 + 2 * d2 + 1];
    Tp[m * 32768 + d2 * 256 + i] = (u32)f2bf(lo) | ((u32)f2bf(hi) << 16);
}

// ---------------- scores: (x.p)/||p|| + mask, plus x -> bf16 conversion ----------------
__global__ __launch_bounds__(256) void k_scores(const float* x, const float* p, const float* mask,
                                                float* scores, u16* xb16) {
    __shared__ float pl[256];
    __shared__ float s_invn;
    int tid = threadIdx.x;
    pl[tid] = p[tid];
    __syncthreads();
    if (tid < 64) {
        float v = pl[tid] * pl[tid] + pl[tid + 64] * pl[tid + 64] +
                  pl[tid + 128] * pl[tid + 128] + pl[tid + 192] * pl[tid + 192];
        for (int o = 32; o > 0; o >>= 1) v += __shfl_xor(v, o);
        if (tid == 0) s_invn = 1.0f / sqrtf(v);
    }
    __syncthreads();
    int wid = tid >> 6, lane = tid & 63;
    for (int it = 0; it < 4; ++it) {
        int node = blockIdx.x * 16 + wid * 4 + it;   // 5000*16 == 80000
        const float* row = x + (size_t)node * DIN + lane * 4;
        float4 u = *(const float4*)row;
        float d = u.x * pl[lane * 4 + 0] + u.y * pl[lane * 4 + 1] +
                  u.z * pl[lane * 4 + 2] + u.w * pl[lane * 4 + 3];
        u32 p0 = (u32)f2bf(u.x) | ((u32)f2bf(u.y) << 16);
        u32 p1 = (u32)f2bf(u.z) | ((u32)f2bf(u.w) << 16);
        *(uint2*)(xb16 + (size_t)node * DIN + lane * 4) = make_uint2(p0, p1);
        for (int o = 32; o > 0; o >>= 1) d += __shfl_xor(d, o);
        if (lane == 0) scores[node] = d * s_invn + mask[node];
    }
}

// ---------------- phase 1: LDS-staged coarse binning ----------------
// Pack: bits [0,17) = t*N+src, [17,25) = dstLocal (0..159), [25,32) = bucket (0..124)
__global__ __launch_bounds__(256) void k_bin(const int* ei, const float* ew,
                                             int* gcur, uint2* binned) {
    int blk = blockIdx.x;                // 0..999
    int t = blk / 250, ci = blk - t * 250;
    int ebase = ci * 2560;
    int tid = threadIdx.x;
    __shared__ u32 hist[128], sc[128], gbase[128];
    __shared__ uint2 stage[2560];
    if (tid < 128) hist[tid] = 0;
    __syncthreads();
    u32 px[10]; u32 pw[10]; u16 rk[10];
#pragma unroll
    for (int k = 0; k < 10; ++k) {
        int e = ebase + tid + k * 256;                  // < E_ exactly
        int dst = ei[t * (2 * E_) + e];
        int src = ei[t * (2 * E_) + E_ + e];
        float w = ew[t * E_ + e];
        int b = dst / BNODES;                           // 0..124
        int dl = dst - b * BNODES;                      // 0..159
        px[k] = (u32)(t * N_ + src) | ((u32)dl << 17) | ((u32)b << 25);
        pw[k] = __float_as_uint(w);
        rk[k] = (u16)atomicAdd(&hist[b], 1u);
    }
    __syncthreads();
    // inclusive scan of hist (125 live, padded to 128)
    if (tid < 128) sc[tid] = hist[tid];
    __syncthreads();
    for (int o = 1; o < 128; o <<= 1) {
        u32 v = 0;
        if (tid < 128) { v = sc[tid]; if (tid >= o) v += sc[tid - o]; }
        __syncthreads();
        if (tid < 128) sc[tid] = v;
        __syncthreads();
    }
    // reserve contiguous global runs (one atomic per bucket per block)
    if (tid < NB) gbase[tid] = (u32)atomicAdd(&gcur[t * NB + tid], (int)hist[tid]);
    // stage into bucket-sorted LDS order: slot = exclusiveStart(b) + rank
#pragma unroll
    for (int k = 0; k < 10; ++k) {
        int b = px[k] >> 25;
        u32 slot = (sc[b] - hist[b]) + rk[k];
        stage[slot] = make_uint2(px[k], pw[k]);
    }
    __syncthreads();
    // flush: consecutive slots -> consecutive global addresses within each bucket run
    for (int s = tid; s < 2560; s += 256) {
        uint2 v = stage[s];
        int b = v.x >> 25;
        u32 local = gbase[b] + ((u32)s - (sc[b] - hist[b]));
        if (local < CAP)
            binned[(size_t)(t * NB + b) * CAP + local] = v;
    }
}

// ---------------- phase 2: in-place per-bucket counting sort by (quarter, band, dl) ----
// Quarter Q = dl/5 owns one CONTIGUOUS run, internally src-band-major -> k_agg's
// inner loop has no band boundaries; band lockstep across quarters is statistical
// (each quarter advances ~17.6 edges/band at the same rate) -> L2-fit preserved.
// Pads (w=0, src=last row, dl spread) land at each quarter's band-9 tail.
// Emits 33 boundaries per bucket: qoff[Q] = binstart[Q*50] (Q<32), CAP (Q=32).
__global__ __launch_bounds__(512) void k_scatter(const int* gcur, uint2* binned, int* bandoff) {
    int bg = blockIdx.x;                 // 0..499
    int t = bg / NB;
    uint2* bucket = binned + (size_t)bg * CAP;
    int cnt = gcur[bg]; if (cnt > CAP) cnt = CAP;
    int tid = threadIdx.x;
    int tbase = t * N_;
    __shared__ u32 nhist[NBIN_PAD];
    __shared__ u32 binstart[NBIN_PAD];
    __shared__ u32 wsum[8];
    for (int i = tid; i < NBIN_PAD; i += 512) nhist[i] = 0;
    __syncthreads();
    u32 vx[11]; u32 vw[11]; u16 r_[11]; u16 bn_[11];
#pragma unroll
    for (int k = 0; k < 11; ++k) {       // 11*512 = 5632 = CAP
        int e = tid + k * 512;
        uint2 v;
        if (e < cnt) {
            v = bucket[e];
        } else {
            // synthetic pad: zero weight, reads a real row, dl spread for balance
            v = make_uint2(((u32)(e % BNODES) << 17) | (u32)(tbase + N_ - 1), 0u);
        }
        vx[k] = v.x; vw[k] = v.y;
        int dl = (v.x >> 17) & 255;
        int s = (int)(v.x & 0x1FFFFu) - tbase;          // 0..19999
        int bin = (dl / 5) * (NSB * 5) + (s >> SGRAN) * 5 + (dl % 5);   // 0..1599
        bn_[k] = (u16)bin;
        r_[k] = (u16)atomicAdd(&nhist[bin], 1u);
    }
    __syncthreads();
    // exclusive scan over 2048 bins: thread sums 4, then scan 512 thread-sums
    u32 loc1, loc2, loc3, tsum;
    {
        int b0 = tid * 4;
        u32 a = nhist[b0], b = nhist[b0 + 1], c = nhist[b0 + 2], d = nhist[b0 + 3];
        loc1 = a; loc2 = a + b; loc3 = a + b + c; tsum = a + b + c + d;
    }
    int lane = tid & 63, wv = tid >> 6;
    u32 xsc = tsum;
    for (int o = 1; o < 64; o <<= 1) { u32 yv = __shfl_up(xsc, o); if (lane >= o) xsc += yv; }
    if (lane == 63) wsum[wv] = xsc;
    __syncthreads();
    u32 wpre = 0;
    for (int wq = 0; wq < wv; ++wq) wpre += wsum[wq];
    u32 tpre = wpre + xsc - tsum;
    {
        int b0 = tid * 4;
        binstart[b0] = tpre;
        binstart[b0 + 1] = tpre + loc1;
        binstart[b0 + 2] = tpre + loc2;
        binstart[b0 + 3] = tpre + loc3;
    }
    __syncthreads();
    if (tid < 33) {
        int v = (tid < 32) ? (int)binstart[tid * (NSB * 5)] : CAP;
        bandoff[bg * BOSTRIDE + tid] = v;
    }
#pragma unroll
    for (int k = 0; k < 11; ++k) {
        u32 pos = binstart[bn_[k]] + r_[k];             // exact permutation of 0..CAP-1
        bucket[pos] = make_uint2(vx[k] & 0x1FFFFFFu, vw[k]);   // keep (dl, src)
    }
}

// ---------------- top-128 (radix select, exact jax order) + xtT build ----------------
__global__ __launch_bounds__(1024) void k_topk(const float* scores, const float* x, float* xtT) {
    int t = blockIdx.x;
    int tid = threadIdx.x;   // 0..1023
    const float* sc = scores + t * N_;
    __shared__ u32 hist[256];
    __shared__ u32 sh_dig, sh_need;
    __shared__ u64 sel[256];
    __shared__ u32 selCount;
    __shared__ u32 idxl[128];
    __shared__ float tvl[128];

    u32 kreg[20];
#pragma unroll
    for (int p = 0; p < 20; ++p) {
        int i = tid + p * 1024;
        kreg[p] = (i < N_) ? fkey(sc[i]) : 0u;
    }

    u32 pref = 0;
    u32 need = 128;
    for (int pass = 0; pass < 4; ++pass) {
        int shift = 24 - 8 * pass;
        if (tid < 256) hist[tid] = 0;
        __syncthreads();
#pragma unroll
        for (int p = 0; p < 20; ++p) {
            int i = tid + p * 1024;
            u32 k = kreg[p];
            bool ok = (i < N_) && ((pass == 0) || ((k >> (shift + 8)) == pref));
            if (ok) atomicAdd(&hist[(k >> shift) & 255u], 1u);
        }
        __syncthreads();
        if (tid < 64) {
            int l = tid;
            u32 s = hist[4 * l] + hist[4 * l + 1] + hist[4 * l + 2] + hist[4 * l + 3];
            u32 S = s;
            for (int o = 1; o < 64; o <<= 1) {
                u32 y = __shfl_down(S, o);
                if (l + o < 64) S += y;
            }
            u64 m = __ballot(S >= need);
            int L = 63 - __builtin_clzll(m);
            if (l == L) {
                u32 Snext = S - s;
                u32 r = 0;
                for (int dd = 3; dd >= 0; --dd) {
                    u32 hb = hist[4 * L + dd];
                    r += hb;
                    if (Snext + r >= need) {
                        sh_dig = (u32)(4 * L + dd);
                        sh_need = need - (Snext + r - hb);
                        break;
                    }
                }
            }
        }
        __syncthreads();
        pref = (pref << 8) | sh_dig;
        need = sh_need;
        __syncthreads();
    }
    if (tid == 0) selCount = 0;
    __syncthreads();
    u32 theta = pref;
#pragma unroll
    for (int p = 0; p < 20; ++p) {
        int i = tid + p * 1024;
        u32 k = kreg[p];
        if (i < N_ && k >= theta) {
            u32 pos = atomicAdd(&selCount, 1u);
            if (pos < 256) sel[pos] = (((u64)(k ^ 0xFFFFFFFFu)) << 32) | (u32)i;
        }
    }
    __syncthreads();
    u32 c = selCount;
    if (c > 256) c = 256;
    if (tid < 256 && (u32)tid >= c) sel[tid] = 0xFFFFFFFFFFFFFFFFull;
    __syncthreads();
    // bitonic ascending sort: key = (~fkey)<<32 | idx  -> value desc, idx asc
    for (int k2 = 2; k2 <= 256; k2 <<= 1) {
        for (int jj = k2 >> 1; jj > 0; jj >>= 1) {
            if (tid < 256) {
                int i = tid, ixj = i ^ jj;
                if (ixj > i) {
                    u64 A = sel[i], B = sel[ixj];
                    bool asc = ((i & k2) == 0);
                    bool sw = asc ? (A > B) : (A < B);
                    if (sw) { sel[i] = B; sel[ixj] = A; }
                }
            }
            __syncthreads();
        }
    }
    if (tid < 128) {
        u64 v = sel[tid];
        u32 k = ((u32)(v >> 32)) ^ 0xFFFFFFFFu;
        idxl[tid] = (u32)(v & 0xFFFFFFFFu);
        tvl[tid] = tanhf(fkeyinv(k));
    }
    __syncthreads();
    float* xt_t = xtT + t * (DIN * DOUT);
    const float* xb = x + (size_t)t * N_ * DIN;
    for (int e2 = tid; e2 < DIN * DOUT; e2 += 1024) {
        int j = e2 >> 8, d = e2 & 255;
        xt_t[e2] = xb[(size_t)idxl[j] * DIN + d] * tvl[j];
    }
}

// ---------------- fused matrix-GRU, all 4 timesteps in one launch -------------------
__global__ __launch_bounds__(256) void k_gru(const float* xtT, const float* W0, const u32* Tp,
                                             const float* bz, const float* br, const float* bh,
                                             u16* WnT) {
    int j0 = blockIdx.x;          // 0..63
    int j1 = j0 + 64;
    int i = threadIdx.x;          // 0..255
    __shared__ float sxt[2][256], sW[2][256], srw[2][256];
    const u32* WzT = Tp;
    const u32* UzT = Tp + 32768;
    const u32* WrT = Tp + 65536;
    const u32* UrT = Tp + 98304;
    const u32* WhT = Tp + 131072;
    const u32* UhT = Tp + 163840;
    float wv0 = W0[i * 128 + j0];
    float wv1 = W0[i * 128 + j1];
    float azb0 = bz[i * 128 + j0], azb1 = bz[i * 128 + j1];
    float arb0 = br[i * 128 + j0], arb1 = br[i * 128 + j1];
    float ahb0 = bh[i * 128 + j0], ahb1 = bh[i * 128 + j1];
    for (int t = 0; t < T_; ++t) {
        __syncthreads();          // previous iteration's LDS reads complete
        sxt[0][i] = xtT[t * 32768 + j0 * 256 + i];
        sxt[1][i] = xtT[t * 32768 + j1 * 256 + i];
        sW[0][i] = wv0;
        sW[1][i] = wv1;
        __syncthreads();
        float az0 = azb0, az1 = azb1, ar0 = arb0, ar1 = arb1;
#pragma unroll 4
        for (int d2 = 0; d2 < 128; ++d2) {
            float x00 = sxt[0][2 * d2], x01 = sxt[0][2 * d2 + 1];
            float x10 = sxt[1][2 * d2], x11 = sxt[1][2 * d2 + 1];
            float w00 = sW[0][2 * d2], w01 = sW[0][2 * d2 + 1];
            float w10 = sW[1][2 * d2], w11 = sW[1][2 * d2 + 1];
            u32 a = WzT[d2 * 256 + i], b = UzT[d2 * 256 + i];
            u32 cc = WrT[d2 * 256 + i], dd = UrT[d2 * 256 + i];
            az0 += blo(a) * x00 + bhi(a) * x01 + blo(b) * w00 + bhi(b) * w01;
            az1 += blo(a) * x10 + bhi(a) * x11 + blo(b) * w10 + bhi(b) * w11;
            ar0 += blo(cc) * x00 + bhi(cc) * x01 + blo(dd) * w00 + bhi(dd) * w01;
            ar1 += blo(cc) * x10 + bhi(cc) * x11 + blo(dd) * w10 + bhi(dd) * w11;
        }
        float z0 = 1.0f / (1.0f + expf(-az0));
        float z1 = 1.0f / (1.0f + expf(-az1));
        float r0 = 1.0f / (1.0f + expf(-ar0));
        float r1 = 1.0f / (1.0f + expf(-ar1));
        srw[0][i] = r0 * wv0;
        srw[1][i] = r1 * wv1;
        __syncthreads();
        float ah0 = ahb0, ah1 = ahb1;
#pragma unroll 4
        for (int d2 = 0; d2 < 128; ++d2) {
            float x00 = sxt[0][2 * d2], x01 = sxt[0][2 * d2 + 1];
            float x10 = sxt[1][2 * d2], x11 = sxt[1][2 * d2 + 1];
            float r00 = srw[0][2 * d2], r01 = srw[0][2 * d2 + 1];
            float r10 = srw[1][2 * d2], r11 = srw[1][2 * d2 + 1];
            u32 a = WhT[d2 * 256 + i], b = UhT[d2 * 256 + i];
            ah0 += blo(a) * x00 + bhi(a) * x01 + blo(b) * r00 + bhi(b) * r01;
            ah1 += blo(a) * x10 + bhi(a) * x11 + blo(b) * r10 + bhi(b) * r11;
        }
        float h0 = tanhf(ah0), h1 = tanhf(ah1);
        float wn0 = (1.0f - z0) * wv0 + z0 * h0;
        float wn1 = (1.0f - z1) * wv1 + z1 * h1;
        WnT[t * 32768 + j0 * 256 + i] = f2bf(wn0);
        WnT[t * 32768 + j1 * 256 + i] = f2bf(wn1);
        wv0 = wn0;
        wv1 = wn1;
    }
}

// ---------------- y = x_bf16 @ Wn (MFMA bf16), batched over t ----------------
__global__ __launch_bounds__(128) void k_gemm(const u16* xb16, const u16* WnT, u16* y) {
    int t = blockIdx.y;
    const u16* xb = xb16 + (size_t)t * N_ * DIN;
    const u16* Bt = WnT + t * (DIN * DOUT);
    u16* yb = y + (size_t)t * N_ * DOUT;
    int wid = threadIdx.x >> 6, lane = threadIdx.x & 63;
    int quad = lane >> 4, lm = lane & 15;
    int rowBase = blockIdx.x * 64 + wid * 32;
    f32x4 acc[2][8];
#pragma unroll
    for (int mi = 0; mi < 2; ++mi)
#pragma unroll
        for (int ni = 0; ni < 8; ++ni) acc[mi][ni] = (f32x4){0.f, 0.f, 0.f, 0.f};
    size_t aoff[2];
#pragma unroll
    for (int mi = 0; mi < 2; ++mi) {
        int r = rowBase + mi * 16 + lm;
        if (r > N_ - 1) r = N_ - 1;
        aoff[mi] = (size_t)r * DIN + quad * 8;
    }
    const u16* bbase = Bt + lm * 256 + quad * 8;
    for (int kk = 0; kk < 256; kk += 32) {
        short8 a0 = *(const short8*)(xb + aoff[0] + kk);
        short8 a1 = *(const short8*)(xb + aoff[1] + kk);
#pragma unroll
        for (int ni = 0; ni < 8; ++ni) {
            short8 b = *(const short8*)(bbase + ni * 4096 + kk);
            acc[0][ni] = __builtin_amdgcn_mfma_f32_16x16x32_bf16(a0, b, acc[0][ni], 0, 0, 0);
            acc[1][ni] = __builtin_amdgcn_mfma_f32_16x16x32_bf16(a1, b, acc[1][ni], 0, 0, 0);
        }
    }
#pragma unroll
    for (int mi = 0; mi < 2; ++mi)
#pragma unroll
        for (int ni = 0; ni < 8; ++ni)
#pragma unroll
            for (int r = 0; r < 4; ++r) {
                int row = rowBase + mi * 16 + quad * 4 + r;
                if (row < N_) yb[(size_t)row * DOUT + ni * 16 + lm] = f2bf(acc[mi][ni][r]);
            }
}

// ---------------- bucket-resident aggregation, quarter-parallel, 4-deep MLP ----------
// One block per (t, bucket): 160 dst rows in 80KB LDS f32, 2 blocks/CU, all 500
// co-resident. Quarter Q (16 lanes) owns dl in [Q*5, Q*5+5) -> exclusive LDS rows,
// no atomics, no barriers. Quarter edges are ONE contiguous run (band-major inside)
// -> inner loop processes 4 edges/iteration: 4 independent meta loads, then 4 y-row
// loads in flight per quarter (16/wave). Band lockstep across quarters keeps the
// per-XCD y footprint ~1 band << 4MB L2 (R4/R6-proven: FETCH ~31MB compulsory).
__global__ __launch_bounds__(512, 4) void k_agg(const uint2* binned, const int* bandoff,
                                                const u16* y, float* out) {
    int bid = blockIdx.x;                 // 0..511 (12 dead)
    int xcd = bid & 7;
    int t = xcd >> 1;
    int bl = ((bid >> 3) << 1) + (xcd & 1);
    if (bl >= NB) return;
    int bg = t * NB + bl;
    const uint2* bucket = binned + (size_t)bg * CAP;
    const int* bo = bandoff + bg * BOSTRIDE;
    int w = threadIdx.x >> 6, lane = threadIdx.x & 63;
    int q = lane >> 4, lq = lane & 15;
    int Q = (w << 2) | q;                 // 0..31
    __shared__ float acc[BNODES][DOUT];   // 80 KB
#pragma unroll
    for (int r = 0; r < 20; ++r)
        *(float2*)&acc[w * 20 + r][2 * lane] = make_float2(0.f, 0.f);
    const u16* yq = y + lq * 8;
    int e = bo[Q];
    int eend = bo[Q + 1];
    int curdl = -1;
    float a0 = 0.f, a1 = 0.f, a2 = 0.f, a3 = 0.f, a4 = 0.f, a5 = 0.f, a6 = 0.f, a7 = 0.f;

#define PROC(mm, vv)                                                    \
    {                                                                   \
        int dl = (int)((mm.x >> 17) & 255u);                            \
        if (dl != curdl) {                                              \
            if (curdl >= 0) {                                           \
                float4* rp = (float4*)&acc[curdl][lq * 8];              \
                float4 r0 = rp[0], r1 = rp[1];                          \
                r0.x += a0; r0.y += a1; r0.z += a2; r0.w += a3;         \
                r1.x += a4; r1.y += a5; r1.z += a6; r1.w += a7;         \
                rp[0] = r0; rp[1] = r1;                                 \
            }                                                           \
            a0 = a1 = a2 = a3 = a4 = a5 = a6 = a7 = 0.f;                \
            curdl = dl;                                                 \
        }                                                               \
        float wt = __uint_as_float(mm.y);                               \
        a0 += wt * blo(vv.x); a1 += wt * bhi(vv.x);                     \
        a2 += wt * blo(vv.y); a3 += wt * bhi(vv.y);                     \
        a4 += wt * blo(vv.z); a5 += wt * bhi(vv.z);                     \
        a6 += wt * blo(vv.w); a7 += wt * bhi(vv.w);                     \
    }

    for (; e + 4 <= eend; e += 4) {
        uint2 m0 = bucket[e];
        uint2 m1 = bucket[e + 1];
        uint2 m2 = bucket[e + 2];
        uint2 m3 = bucket[e + 3];
        uint4 v0 = *(const uint4*)(yq + (size_t)(m0.x & 0x1FFFFu) * DOUT);
        uint4 v1 = *(const uint4*)(yq + (size_t)(m1.x & 0x1FFFFu) * DOUT);
        uint4 v2 = *(const uint4*)(yq + (size_t)(m2.x & 0x1FFFFu) * DOUT);
        uint4 v3 = *(const uint4*)(yq + (size_t)(m3.x & 0x1FFFFu) * DOUT);
        PROC(m0, v0)
        PROC(m1, v1)
        PROC(m2, v2)
        PROC(m3, v3)
    }
    for (; e < eend; ++e) {
        uint2 m = bucket[e];
        uint4 v = *(const uint4*)(yq + (size_t)(m.x & 0x1FFFFu) * DOUT);
        PROC(m, v)
    }
    if (curdl >= 0) {
        float4* rp = (float4*)&acc[curdl][lq * 8];
        float4 r0 = rp[0], r1 = rp[1];
        r0.x += a0; r0.y += a1; r0.z += a2; r0.w += a3;
        r1.x += a4; r1.y += a5; r1.z += a6; r1.w += a7;
        rp[0] = r0; rp[1] = r1;
    }
#undef PROC
    // epilogue: RReLU + coalesced store of the wave's own 20 rows (same-wave order)
    int gbase = t * N_ + bl * BNODES + w * 20;
#pragma unroll
    for (int r = 0; r < 20; ++r) {
        float v0 = acc[w * 20 + r][2 * lane], v1 = acc[w * 20 + r][2 * lane + 1];
        v0 = (v0 >= 0.f) ? v0 : SLOPE * v0;
        v1 = (v1 >= 0.f) ? v1 : SLOPE * v1;
        *(float2*)(out + (size_t)(gbase + r) * DOUT + 2 * lane) = make_float2(v0, v1);
    }
}

extern "C" void kernel_launch(void* const* d_in, const int* in_sizes, int n_in,
                              void* d_out, int out_size, void* d_ws, size_t ws_size,
                              hipStream_t stream) {
    const float* x = (const float*)d_in[0];
    const int* ei = (const int*)d_in[1];
    const float* ew = (const float*)d_in[2];
    const float* mask = (const float*)d_in[3];
    const float* p = (const float*)d_in[4];
    const float* Wz = (const float*)d_in[5];
    const float* Uz = (const float*)d_in[6];
    const float* bz = (const float*)d_in[7];
    const float* Wr = (const float*)d_in[8];
    const float* Ur = (const float*)d_in[9];
    const float* br = (const float*)d_in[10];
    const float* Wh = (const float*)d_in[11];
    const float* Uh = (const float*)d_in[12];
    const float* bh = (const float*)d_in[13];
    const float* W0 = (const float*)d_in[14];
    float* out = (float*)d_out;

    char* w = (char*)d_ws;
    u16* xb16 = (u16*)w;        w += (size_t)NT * DIN * 2;        // 40,960,000
    float* scores = (float*)w;  w += 320256;                      // NT f32
    float* xtT = (float*)w;     w += 4 * 32768 * 4;               // [t][128][256] f32
    u16* WnT = (u16*)w;         w += 4 * 32768 * 2;               // [t][128][256] bf16
    u32* Tp = (u32*)w;          w += 6 * 32768 * 4;               // packed transposed weights
    u16* y = (u16*)w;           w += (size_t)NT * DOUT * 2;       // [t][N][128] bf16
    uint2* binned = (uint2*)w;  w += (size_t)NBTOT * CAP * 8;     // bucketed edges (in-place sort)
    int* gcur = (int*)w;        w += 2048;                        // 500 bucket cursors
    int* bandoff = (int*)w;     w += NBTOT * BOSTRIDE * 4;        // [bucket][33 boundaries]

    hipMemsetAsync(gcur, 0, 2048, stream);

    k_transpose<<<768, 256, 0, stream>>>(Wz, Uz, Wr, Ur, Wh, Uh, Tp);
    k_scores<<<5000, 256, 0, stream>>>(x, p, mask, scores, xb16);
    k_bin<<<1000, 256, 0, stream>>>(ei, ew, gcur, binned);
    k_scatter<<<NBTOT, 512, 0, stream>>>(gcur, binned, bandoff);
    k_topk<<<4, 1024, 0, stream>>>(scores, x, xtT);
    k_gru<<<64, 256, 0, stream>>>(xtT, W0, Tp, bz, br, bh, WnT);
    k_gemm<<<dim3(313, 4), 128, 0, stream>>>(xb16, WnT, y);
    k_agg<<<512, 512, 0, stream>>>(binned, bandoff, y, out);
}

// Round 8
// 406.524 us; speedup vs baseline: 1.6072x; 1.0602x over previous
//
#include <hip/hip_runtime.h>

typedef unsigned short u16;
typedef unsigned int u32;
typedef unsigned long long u64;

#define T_ 4
#define N_ 20000
#define E_ 640000
#define DIN 256
#define DOUT 128
#define NT (T_*N_)          // 80000
#define TE (T_*E_)          // 2560000
#define SLOPE 0.22916666666666666f

// coarse binning geometry: 125 buckets of 160 nodes per timestep
#define NB 125
#define BNODES 160
#define CAP 5632            // mean 5120, sigma ~72 -> 14 sigma headroom
#define NBTOT (T_*NB)       // 500

// k_scatter composite sort key: (quarter = dl/5, src band, dl%5)
// -> each k_agg quarter owns ONE contiguous run, internally src-band-major
#define SGRAN 11
#define NSB 10              // ceil(20000 / 2048)
#define NBIN (32*NSB*5)     // 1600
#define NBIN_PAD 2048
#define BOSTRIDE 40         // 33 boundaries per bucket, padded

typedef __attribute__((ext_vector_type(8))) short short8;
typedef __attribute__((ext_vector_type(4))) float f32x4;

__device__ __forceinline__ float blo(u32 u) { return __uint_as_float(u << 16); }
__device__ __forceinline__ float bhi(u32 u) { return __uint_as_float(u & 0xFFFF0000u); }
__device__ __forceinline__ u16 f2bf(float f) {
    u32 u = __float_as_uint(f);
    return (u16)((u + 0x7FFFu + ((u >> 16) & 1u)) >> 16);
}
__device__ __forceinline__ u32 fkey(float f) {
    u32 u = __float_as_uint(f);
    return (u & 0x80000000u) ? ~u : (u | 0x80000000u);
}
__device__ __forceinline__ float fkeyinv(u32 k) {
    u32 u = (k & 0x80000000u) ? (k ^ 0x80000000u) : ~k;
    return __uint_as_float(u);
}

// ---------------- transpose+pack the 6 GRU weight matrices (f32 -> bf16 pairs) ------
__global__ void k_transpose(const float* Wz, const float* Uz, const float* Wr, const float* Ur,
                            const float* Wh, const float* Uh, u32* Tp) {
    int bid = blockIdx.x;
    int m = bid >> 7, b = bid & 127;
    int idx = b * 256 + threadIdx.x;      // 0..32767
    int d2 = idx & 127, i = idx >> 7;     // coalesced f32 pair reads
    const float* src;
    switch (m) {
        case 0: src = Wz; break;
        case 1: src = Uz; break;
        case 2: src = Wr; break;
        case 3: src = Ur; break;
        case 4: src = Wh; break;
        default: src = Uh; break;
    }
    float lo = src[i * 256 + 2 * d2];
    float hi = src[i * 256 + 2 * d2 + 1];
    Tp[m * 32768 + d2 * 256 + i] = (u32)f2bf(lo) | ((u32)f2bf(hi) << 16);
}

// ---------------- scores: (x.p)/||p|| + mask, plus x -> bf16 conversion ----------------
__global__ __launch_bounds__(256) void k_scores(const float* x, const float* p, const float* mask,
                                                float* scores, u16* xb16) {
    __shared__ float pl[256];
    __shared__ float s_invn;
    int tid = threadIdx.x;
    pl[tid] = p[tid];
    __syncthreads();
    if (tid < 64) {
        float v = pl[tid] * pl[tid] + pl[tid + 64] * pl[tid + 64] +
                  pl[tid + 128] * pl[tid + 128] + pl[tid + 192] * pl[tid + 192];
        for (int o = 32; o > 0; o >>= 1) v += __shfl_xor(v, o);
        if (tid == 0) s_invn = 1.0f / sqrtf(v);
    }
    __syncthreads();
    int wid = tid >> 6, lane = tid & 63;
    for (int it = 0; it < 4; ++it) {
        int node = blockIdx.x * 16 + wid * 4 + it;   // 5000*16 == 80000
        const float* row = x + (size_t)node * DIN + lane * 4;
        float4 u = *(const float4*)row;
        float d = u.x * pl[lane * 4 + 0] + u.y * pl[lane * 4 + 1] +
                  u.z * pl[lane * 4 + 2] + u.w * pl[lane * 4 + 3];
        u32 p0 = (u32)f2bf(u.x) | ((u32)f2bf(u.y) << 16);
        u32 p1 = (u32)f2bf(u.z) | ((u32)f2bf(u.w) << 16);
        *(uint2*)(xb16 + (size_t)node * DIN + lane * 4) = make_uint2(p0, p1);
        for (int o = 32; o > 0; o >>= 1) d += __shfl_xor(d, o);
        if (lane == 0) scores[node] = d * s_invn + mask[node];
    }
}

// ---------------- phase 1: LDS-staged coarse binning ----------------
// Pack: bits [0,17) = t*N+src, [17,25) = dstLocal (0..159), [25,32) = bucket (0..124)
__global__ __launch_bounds__(256) void k_bin(const int* ei, const float* ew,
                                             int* gcur, uint2* binned) {
    int blk = blockIdx.x;                // 0..999
    int t = blk / 250, ci = blk - t * 250;
    int ebase = ci * 2560;
    int tid = threadIdx.x;
    __shared__ u32 hist[128], sc[128], gbase[128];
    __shared__ uint2 stage[2560];
    if (tid < 128) hist[tid] = 0;
    __syncthreads();
    u32 px[10]; u32 pw[10]; u16 rk[10];
#pragma unroll
    for (int k = 0; k < 10; ++k) {
        int e = ebase + tid + k * 256;                  // < E_ exactly
        int dst = ei[t * (2 * E_) + e];
        int src = ei[t * (2 * E_) + E_ + e];
        float w = ew[t * E_ + e];
        int b = dst / BNODES;                           // 0..124
        int dl = dst - b * BNODES;                      // 0..159
        px[k] = (u32)(t * N_ + src) | ((u32)dl << 17) | ((u32)b << 25);
        pw[k] = __float_as_uint(w);
        rk[k] = (u16)atomicAdd(&hist[b], 1u);
    }
    __syncthreads();
    // inclusive scan of hist (125 live, padded to 128)
    if (tid < 128) sc[tid] = hist[tid];
    __syncthreads();
    for (int o = 1; o < 128; o <<= 1) {
        u32 v = 0;
        if (tid < 128) { v = sc[tid]; if (tid >= o) v += sc[tid - o]; }
        __syncthreads();
        if (tid < 128) sc[tid] = v;
        __syncthreads();
    }
    // reserve contiguous global runs (one atomic per bucket per block)
    if (tid < NB) gbase[tid] = (u32)atomicAdd(&gcur[t * NB + tid], (int)hist[tid]);
    // stage into bucket-sorted LDS order: slot = exclusiveStart(b) + rank
#pragma unroll
    for (int k = 0; k < 10; ++k) {
        int b = px[k] >> 25;
        u32 slot = (sc[b] - hist[b]) + rk[k];
        stage[slot] = make_uint2(px[k], pw[k]);
    }
    __syncthreads();
    // flush: consecutive slots -> consecutive global addresses within each bucket run
    for (int s = tid; s < 2560; s += 256) {
        uint2 v = stage[s];
        int b = v.x >> 25;
        u32 local = gbase[b] + ((u32)s - (sc[b] - hist[b]));
        if (local < CAP)
            binned[(size_t)(t * NB + b) * CAP + local] = v;
    }
}

// ---------------- phase 2: in-place per-bucket counting sort by (quarter, band, dl) ----
// Quarter Q = dl/5 owns one CONTIGUOUS run, internally src-band-major -> k_agg's
// inner loop has no band boundaries; band lockstep across quarters is statistical
// (each quarter advances ~17.6 edges/band at the same rate) -> L2-fit preserved.
// Pads (w=0, src=last row, dl spread) land at each quarter's band-9 tail.
// Emits 33 boundaries per bucket: qoff[Q] = binstart[Q*50] (Q<32), CAP (Q=32).
__global__ __launch_bounds__(512) void k_scatter(const int* gcur, uint2* binned, int* bandoff) {
    int bg = blockIdx.x;                 // 0..499
    int t = bg / NB;
    uint2* bucket = binned + (size_t)bg * CAP;
    int cnt = gcur[bg]; if (cnt > CAP) cnt = CAP;
    int tid = threadIdx.x;
    int tbase = t * N_;
    __shared__ u32 nhist[NBIN_PAD];
    __shared__ u32 binstart[NBIN_PAD];
    __shared__ u32 wsum[8];
    for (int i = tid; i < NBIN_PAD; i += 512) nhist[i] = 0;
    __syncthreads();
    u32 vx[11]; u32 vw[11]; u16 r_[11]; u16 bn_[11];
#pragma unroll
    for (int k = 0; k < 11; ++k) {       // 11*512 = 5632 = CAP
        int e = tid + k * 512;
        uint2 v;
        if (e < cnt) {
            v = bucket[e];
        } else {
            // synthetic pad: zero weight, reads a real row, dl spread for balance
            v = make_uint2(((u32)(e % BNODES) << 17) | (u32)(tbase + N_ - 1), 0u);
        }
        vx[k] = v.x; vw[k] = v.y;
        int dl = (v.x >> 17) & 255;
        int s = (int)(v.x & 0x1FFFFu) - tbase;          // 0..19999
        int bin = (dl / 5) * (NSB * 5) + (s >> SGRAN) * 5 + (dl % 5);   // 0..1599
        bn_[k] = (u16)bin;
        r_[k] = (u16)atomicAdd(&nhist[bin], 1u);
    }
    __syncthreads();
    // exclusive scan over 2048 bins: thread sums 4, then scan 512 thread-sums
    u32 loc1, loc2, loc3, tsum;
    {
        int b0 = tid * 4;
        u32 a = nhist[b0], b = nhist[b0 + 1], c = nhist[b0 + 2], d = nhist[b0 + 3];
        loc1 = a; loc2 = a + b; loc3 = a + b + c; tsum = a + b + c + d;
    }
    int lane = tid & 63, wv = tid >> 6;
    u32 xsc = tsum;
    for (int o = 1; o < 64; o <<= 1) { u32 yv = __shfl_up(xsc, o); if (lane >= o) xsc += yv; }
    if (lane == 63) wsum[wv] = xsc;
    __syncthreads();
    u32 wpre = 0;
    for (int wq = 0; wq < wv; ++wq) wpre += wsum[wq];
    u32 tpre = wpre + xsc - tsum;
    {
        int b0 = tid * 4;
        binstart[b0] = tpre;
        binstart[b0 + 1] = tpre + loc1;
        binstart[b0 + 2] = tpre + loc2;
        binstart[b0 + 3] = tpre + loc3;
    }
    __syncthreads();
    if (tid < 33) {
        int v = (tid < 32) ? (int)binstart[tid * (NSB * 5)] : CAP;
        bandoff[bg * BOSTRIDE + tid] = v;
    }
#pragma unroll
    for (int k = 0; k < 11; ++k) {
        u32 pos = binstart[bn_[k]] + r_[k];             // exact permutation of 0..CAP-1
        bucket[pos] = make_uint2(vx[k] & 0x1FFFFFFu, vw[k]);   // keep (dl, src)
    }
}

// ---------------- top-128 (radix select, exact jax order) + xtT build ----------------
__global__ __launch_bounds__(1024) void k_topk(const float* scores, const float* x, float* xtT) {
    int t = blockIdx.x;
    int tid = threadIdx.x;   // 0..1023
    const float* sc = scores + t * N_;
    __shared__ u32 hist[256];
    __shared__ u32 sh_dig, sh_need;
    __shared__ u64 sel[256];
    __shared__ u32 selCount;
    __shared__ u32 idxl[128];
    __shared__ float tvl[128];

    u32 kreg[20];
#pragma unroll
    for (int p = 0; p < 20; ++p) {
        int i = tid + p * 1024;
        kreg[p] = (i < N_) ? fkey(sc[i]) : 0u;
    }

    u32 pref = 0;
    u32 need = 128;
    for (int pass = 0; pass < 4; ++pass) {
        int shift = 24 - 8 * pass;
        if (tid < 256) hist[tid] = 0;
        __syncthreads();
#pragma unroll
        for (int p = 0; p < 20; ++p) {
            int i = tid + p * 1024;
            u32 k = kreg[p];
            bool ok = (i < N_) && ((pass == 0) || ((k >> (shift + 8)) == pref));
            if (ok) atomicAdd(&hist[(k >> shift) & 255u], 1u);
        }
        __syncthreads();
        if (tid < 64) {
            int l = tid;
            u32 s = hist[4 * l] + hist[4 * l + 1] + hist[4 * l + 2] + hist[4 * l + 3];
            u32 S = s;
            for (int o = 1; o < 64; o <<= 1) {
                u32 y = __shfl_down(S, o);
                if (l + o < 64) S += y;
            }
            u64 m = __ballot(S >= need);
            int L = 63 - __builtin_clzll(m);
            if (l == L) {
                u32 Snext = S - s;
                u32 r = 0;
                for (int dd = 3; dd >= 0; --dd) {
                    u32 hb = hist[4 * L + dd];
                    r += hb;
                    if (Snext + r >= need) {
                        sh_dig = (u32)(4 * L + dd);
                        sh_need = need - (Snext + r - hb);
                        break;
                    }
                }
            }
        }
        __syncthreads();
        pref = (pref << 8) | sh_dig;
        need = sh_need;
        __syncthreads();
    }
    if (tid == 0) selCount = 0;
    __syncthreads();
    u32 theta = pref;
#pragma unroll
    for (int p = 0; p < 20; ++p) {
        int i = tid + p * 1024;
        u32 k = kreg[p];
        if (i < N_ && k >= theta) {
            u32 pos = atomicAdd(&selCount, 1u);
            if (pos < 256) sel[pos] = (((u64)(k ^ 0xFFFFFFFFu)) << 32) | (u32)i;
        }
    }
    __syncthreads();
    u32 c = selCount;
    if (c > 256) c = 256;
    if (tid < 256 && (u32)tid >= c) sel[tid] = 0xFFFFFFFFFFFFFFFFull;
    __syncthreads();
    // bitonic ascending sort: key = (~fkey)<<32 | idx  -> value desc, idx asc
    for (int k2 = 2; k2 <= 256; k2 <<= 1) {
        for (int jj = k2 >> 1; jj > 0; jj >>= 1) {
            if (tid < 256) {
                int i = tid, ixj = i ^ jj;
                if (ixj > i) {
                    u64 A = sel[i], B = sel[ixj];
                    bool asc = ((i & k2) == 0);
                    bool sw = asc ? (A > B) : (A < B);
                    if (sw) { sel[i] = B; sel[ixj] = A; }
                }
            }
            __syncthreads();
        }
    }
    if (tid < 128) {
        u64 v = sel[tid];
        u32 k = ((u32)(v >> 32)) ^ 0xFFFFFFFFu;
        idxl[tid] = (u32)(v & 0xFFFFFFFFu);
        tvl[tid] = tanhf(fkeyinv(k));
    }
    __syncthreads();
    float* xt_t = xtT + t * (DIN * DOUT);
    const float* xb = x + (size_t)t * N_ * DIN;
    for (int e2 = tid; e2 < DIN * DOUT; e2 += 1024) {
        int j = e2 >> 8, d = e2 & 255;
        xt_t[e2] = xb[(size_t)idxl[j] * DIN + d] * tvl[j];
    }
}

// ---------------- fused matrix-GRU, all 4 timesteps, split-K for occupancy ----------
// One block per COLUMN j (128 blocks), 512 threads = (row i, d-half h). Each thread
// accumulates its gate dot-product over 64 of 128 d-pairs; halves combine via a
// 2-entry LDS reduction (bias added post-reduction). Both halves redundantly compute
// z/r/Wn from the shared sums so the register-carried wv stays consistent.
// vs R7: 2x blocks, 2x waves/block, 1/4 serial chain per thread -> latency-bound
// 86us expected to drop ~3x (was 64 CUs x 1 wave/SIMD; now 128 CUs x 2 waves/SIMD).
__global__ __launch_bounds__(512) void k_gru(const float* xtT, const float* W0, const u32* Tp,
                                             const float* bz, const float* br, const float* bh,
                                             u16* WnT) {
    int j = blockIdx.x;           // 0..127 column
    int tid = threadIdx.x;        // 0..511
    int i = tid & 255;            // row
    int h = tid >> 8;             // d-half
    __shared__ float sxt[256], sW[256], srw[256];
    __shared__ float p1[2][256], p2[2][256];
    const u32* WzT = Tp;
    const u32* UzT = Tp + 32768;
    const u32* WrT = Tp + 65536;
    const u32* UrT = Tp + 98304;
    const u32* WhT = Tp + 131072;
    const u32* UhT = Tp + 163840;
    float wv = W0[i * 128 + j];
    float azb = bz[i * 128 + j];
    float arb = br[i * 128 + j];
    float ahb = bh[i * 128 + j];
    int d2base = h * 64;
    for (int t = 0; t < T_; ++t) {
        __syncthreads();          // prior iteration's p1 reads complete
        if (h == 0) {
            sxt[i] = xtT[t * 32768 + j * 256 + i];
            sW[i] = wv;
        }
        __syncthreads();
        float az = 0.f, ar = 0.f;
#pragma unroll 4
        for (int dd = 0; dd < 64; ++dd) {
            int d2 = d2base + dd;
            float x0 = sxt[2 * d2], x1 = sxt[2 * d2 + 1];
            float w0 = sW[2 * d2], w1 = sW[2 * d2 + 1];
            u32 a = WzT[d2 * 256 + i], b = UzT[d2 * 256 + i];
            u32 cc = WrT[d2 * 256 + i], dv = UrT[d2 * 256 + i];
            az += blo(a) * x0 + bhi(a) * x1 + blo(b) * w0 + bhi(b) * w1;
            ar += blo(cc) * x0 + bhi(cc) * x1 + blo(dv) * w0 + bhi(dv) * w1;
        }
        p1[h][i] = az;
        p2[h][i] = ar;
        __syncthreads();
        float azs = p1[0][i] + p1[1][i] + azb;
        float ars = p2[0][i] + p2[1][i] + arb;
        float z = 1.0f / (1.0f + expf(-azs));
        float r = 1.0f / (1.0f + expf(-ars));
        if (h == 0) srw[i] = r * wv;
        __syncthreads();          // srw ready; also guards p1 reuse below
        float ah = 0.f;
#pragma unroll 4
        for (int dd = 0; dd < 64; ++dd) {
            int d2 = d2base + dd;
            float x0 = sxt[2 * d2], x1 = sxt[2 * d2 + 1];
            float r0 = srw[2 * d2], r1 = srw[2 * d2 + 1];
            u32 a = WhT[d2 * 256 + i], b = UhT[d2 * 256 + i];
            ah += blo(a) * x0 + bhi(a) * x1 + blo(b) * r0 + bhi(b) * r1;
        }
        p1[h][i] = ah;
        __syncthreads();
        float ahs = p1[0][i] + p1[1][i] + ahb;
        float hh = tanhf(ahs);
        float wn = (1.0f - z) * wv + z * hh;
        if (h == 0) WnT[t * 32768 + j * 256 + i] = f2bf(wn);
        wv = wn;
    }
}

// ---------------- y = x_bf16 @ Wn (MFMA bf16), batched over t ----------------
__global__ __launch_bounds__(128) void k_gemm(const u16* xb16, const u16* WnT, u16* y) {
    int t = blockIdx.y;
    const u16* xb = xb16 + (size_t)t * N_ * DIN;
    const u16* Bt = WnT + t * (DIN * DOUT);
    u16* yb = y + (size_t)t * N_ * DOUT;
    int wid = threadIdx.x >> 6, lane = threadIdx.x & 63;
    int quad = lane >> 4, lm = lane & 15;
    int rowBase = blockIdx.x * 64 + wid * 32;
    f32x4 acc[2][8];
#pragma unroll
    for (int mi = 0; mi < 2; ++mi)
#pragma unroll
        for (int ni = 0; ni < 8; ++ni) acc[mi][ni] = (f32x4){0.f, 0.f, 0.f, 0.f};
    size_t aoff[2];
#pragma unroll
    for (int mi = 0; mi < 2; ++mi) {
        int r = rowBase + mi * 16 + lm;
        if (r > N_ - 1) r = N_ - 1;
        aoff[mi] = (size_t)r * DIN + quad * 8;
    }
    const u16* bbase = Bt + lm * 256 + quad * 8;
    for (int kk = 0; kk < 256; kk += 32) {
        short8 a0 = *(const short8*)(xb + aoff[0] + kk);
        short8 a1 = *(const short8*)(xb + aoff[1] + kk);
#pragma unroll
        for (int ni = 0; ni < 8; ++ni) {
            short8 b = *(const short8*)(bbase + ni * 4096 + kk);
            acc[0][ni] = __builtin_amdgcn_mfma_f32_16x16x32_bf16(a0, b, acc[0][ni], 0, 0, 0);
            acc[1][ni] = __builtin_amdgcn_mfma_f32_16x16x32_bf16(a1, b, acc[1][ni], 0, 0, 0);
        }
    }
#pragma unroll
    for (int mi = 0; mi < 2; ++mi)
#pragma unroll
        for (int ni = 0; ni < 8; ++ni)
#pragma unroll
            for (int r = 0; r < 4; ++r) {
                int row = rowBase + mi * 16 + quad * 4 + r;
                if (row < N_) yb[(size_t)row * DOUT + ni * 16 + lm] = f2bf(acc[mi][ni][r]);
            }
}

// ---------------- bucket-resident aggregation, quarter-parallel, 4-deep MLP ----------
__global__ __launch_bounds__(512, 4) void k_agg(const uint2* binned, const int* bandoff,
                                                const u16* y, float* out) {
    int bid = blockIdx.x;                 // 0..511 (12 dead)
    int xcd = bid & 7;
    int t = xcd >> 1;
    int bl = ((bid >> 3) << 1) + (xcd & 1);
    if (bl >= NB) return;
    int bg = t * NB + bl;
    const uint2* bucket = binned + (size_t)bg * CAP;
    const int* bo = bandoff + bg * BOSTRIDE;
    int w = threadIdx.x >> 6, lane = threadIdx.x & 63;
    int q = lane >> 4, lq = lane & 15;
    int Q = (w << 2) | q;                 // 0..31
    __shared__ float acc[BNODES][DOUT];   // 80 KB
#pragma unroll
    for (int r = 0; r < 20; ++r)
        *(float2*)&acc[w * 20 + r][2 * lane] = make_float2(0.f, 0.f);
    const u16* yq = y + lq * 8;
    int e = bo[Q];
    int eend = bo[Q + 1];
    int curdl = -1;
    float a0 = 0.f, a1 = 0.f, a2 = 0.f, a3 = 0.f, a4 = 0.f, a5 = 0.f, a6 = 0.f, a7 = 0.f;

#define PROC(mm, vv)                                                    \
    {                                                                   \
        int dl = (int)((mm.x >> 17) & 255u);                            \
        if (dl != curdl) {                                              \
            if (curdl >= 0) {                                           \
                float4* rp = (float4*)&acc[curdl][lq * 8];              \
                float4 r0 = rp[0], r1 = rp[1];                          \
                r0.x += a0; r0.y += a1; r0.z += a2; r0.w += a3;         \
                r1.x += a4; r1.y += a5; r1.z += a6; r1.w += a7;         \
                rp[0] = r0; rp[1] = r1;                                 \
            }                                                           \
            a0 = a1 = a2 = a3 = a4 = a5 = a6 = a7 = 0.f;                \
            curdl = dl;                                                 \
        }                                                               \
        float wt = __uint_as_float(mm.y);                               \
        a0 += wt * blo(vv.x); a1 += wt * bhi(vv.x);                     \
        a2 += wt * blo(vv.y); a3 += wt * bhi(vv.y);                     \
        a4 += wt * blo(vv.z); a5 += wt * bhi(vv.z);                     \
        a6 += wt * blo(vv.w); a7 += wt * bhi(vv.w);                     \
    }

    for (; e + 4 <= eend; e += 4) {
        uint2 m0 = bucket[e];
        uint2 m1 = bucket[e + 1];
        uint2 m2 = bucket[e + 2];
        uint2 m3 = bucket[e + 3];
        uint4 v0 = *(const uint4*)(yq + (size_t)(m0.x & 0x1FFFFu) * DOUT);
        uint4 v1 = *(const uint4*)(yq + (size_t)(m1.x & 0x1FFFFu) * DOUT);
        uint4 v2 = *(const uint4*)(yq + (size_t)(m2.x & 0x1FFFFu) * DOUT);
        uint4 v3 = *(const uint4*)(yq + (size_t)(m3.x & 0x1FFFFu) * DOUT);
        PROC(m0, v0)
        PROC(m1, v1)
        PROC(m2, v2)
        PROC(m3, v3)
    }
    for (; e < eend; ++e) {
        uint2 m = bucket[e];
        uint4 v = *(const uint4*)(yq + (size_t)(m.x & 0x1FFFFu) * DOUT);
        PROC(m, v)
    }
    if (curdl >= 0) {
        float4* rp = (float4*)&acc[curdl][lq * 8];
        float4 r0 = rp[0], r1 = rp[1];
        r0.x += a0; r0.y += a1; r0.z += a2; r0.w += a3;
        r1.x += a4; r1.y += a5; r1.z += a6; r1.w += a7;
        rp[0] = r0; rp[1] = r1;
    }
#undef PROC
    // epilogue: RReLU + coalesced store of the wave's own 20 rows (same-wave order)
    int gbase = t * N_ + bl * BNODES + w * 20;
#pragma unroll
    for (int r = 0; r < 20; ++r) {
        float v0 = acc[w * 20 + r][2 * lane], v1 = acc[w * 20 + r][2 * lane + 1];
        v0 = (v0 >= 0.f) ? v0 : SLOPE * v0;
        v1 = (v1 >= 0.f) ? v1 : SLOPE * v1;
        *(float2*)(out + (size_t)(gbase + r) * DOUT + 2 * lane) = make_float2(v0, v1);
    }
}

extern "C" void kernel_launch(void* const* d_in, const int* in_sizes, int n_in,
                              void* d_out, int out_size, void* d_ws, size_t ws_size,
                              hipStream_t stream) {
    const float* x = (const float*)d_in[0];
    const int* ei = (const int*)d_in[1];
    const float* ew = (const float*)d_in[2];
    const float* mask = (const float*)d_in[3];
    const float* p = (const float*)d_in[4];
    const float* Wz = (const float*)d_in[5];
    const float* Uz = (const float*)d_in[6];
    const float* bz = (const float*)d_in[7];
    const float* Wr = (const float*)d_in[8];
    const float* Ur = (const float*)d_in[9];
    const float* br = (const float*)d_in[10];
    const float* Wh = (const float*)d_in[11];
    const float* Uh = (const float*)d_in[12];
    const float* bh = (const float*)d_in[13];
    const float* W0 = (const float*)d_in[14];
    float* out = (float*)d_out;

    char* w = (char*)d_ws;
    u16* xb16 = (u16*)w;        w += (size_t)NT * DIN * 2;        // 40,960,000
    float* scores = (float*)w;  w += 320256;                      // NT f32
    float* xtT = (float*)w;     w += 4 * 32768 * 4;               // [t][128][256] f32
    u16* WnT = (u16*)w;         w += 4 * 32768 * 2;               // [t][128][256] bf16
    u32* Tp = (u32*)w;          w += 6 * 32768 * 4;               // packed transposed weights
    u16* y = (u16*)w;           w += (size_t)NT * DOUT * 2;       // [t][N][128] bf16
    uint2* binned = (uint2*)w;  w += (size_t)NBTOT * CAP * 8;     // bucketed edges (in-place sort)
    int* gcur = (int*)w;        w += 2048;                        // 500 bucket cursors
    int* bandoff = (int*)w;     w += NBTOT * BOSTRIDE * 4;        // [bucket][33 boundaries]

    hipMemsetAsync(gcur, 0, 2048, stream);

    k_transpose<<<768, 256, 0, stream>>>(Wz, Uz, Wr, Ur, Wh, Uh, Tp);
    k_scores<<<5000, 256, 0, stream>>>(x, p, mask, scores, xb16);
    k_bin<<<1000, 256, 0, stream>>>(ei, ew, gcur, binned);
    k_scatter<<<NBTOT, 512, 0, stream>>>(gcur, binned, bandoff);
    k_topk<<<4, 1024, 0, stream>>>(scores, x, xtT);
    k_gru<<<128, 512, 0, stream>>>(xtT, W0, Tp, bz, br, bh, WnT);
    k_gemm<<<dim3(313, 4), 128, 0, stream>>>(xb16, WnT, y);
    k_agg<<<512, 512, 0, stream>>>(binned, bandoff, y, out);
}

// Round 9
// 386.451 us; speedup vs baseline: 1.6906x; 1.0519x over previous
//
#include <hip/hip_runtime.h>

typedef unsigned short u16;
typedef unsigned int u32;
typedef unsigned long long u64;

#define T_ 4
#define N_ 20000
#define E_ 640000
#define DIN 256
#define DOUT 128
#define NT (T_*N_)          // 80000
#define TE (T_*E_)          // 2560000
#define SLOPE 0.22916666666666666f

// coarse binning geometry: 125 buckets of 160 nodes per timestep
#define NB 125
#define BNODES 160
#define CAP 5632            // mean 5120, sigma ~72 -> 14 sigma headroom
#define NBTOT (T_*NB)       // 500

// k_scatter composite sort key: (quarter = dl/5, src band, dl%5)
// -> each k_agg quarter owns ONE contiguous run, internally src-band-major
#define SGRAN 11
#define NSB 10              // ceil(20000 / 2048)
#define NBIN (32*NSB*5)     // 1600
#define NBIN_PAD 2048
#define BOSTRIDE 40         // 33 boundaries per bucket, padded

typedef __attribute__((ext_vector_type(8))) short short8;
typedef __attribute__((ext_vector_type(4))) float f32x4;

__device__ __forceinline__ float blo(u32 u) { return __uint_as_float(u << 16); }
__device__ __forceinline__ float bhi(u32 u) { return __uint_as_float(u & 0xFFFF0000u); }
__device__ __forceinline__ u16 f2bf(float f) {
    u32 u = __float_as_uint(f);
    return (u16)((u + 0x7FFFu + ((u >> 16) & 1u)) >> 16);
}
__device__ __forceinline__ u32 fkey(float f) {
    u32 u = __float_as_uint(f);
    return (u & 0x80000000u) ? ~u : (u | 0x80000000u);
}
__device__ __forceinline__ float fkeyinv(u32 k) {
    u32 u = (k & 0x80000000u) ? (k ^ 0x80000000u) : ~k;
    return __uint_as_float(u);
}

// ---------------- scores (+ fused weight transpose in blocks 5000..5767) -------------
__global__ __launch_bounds__(256) void k_scores(const float* x, const float* p, const float* mask,
                                                float* scores, u16* xb16,
                                                const float* Wz, const float* Uz, const float* Wr,
                                                const float* Ur, const float* Wh, const float* Uh,
                                                u32* Tp) {
    int tid = threadIdx.x;
    if (blockIdx.x >= 5000) {
        // transpose+pack the 6 GRU weight matrices (f32 -> bf16 pairs)
        int bid = blockIdx.x - 5000;      // 0..767
        int m = bid >> 7, b = bid & 127;
        int idx = b * 256 + tid;          // 0..32767
        int d2 = idx & 127, i = idx >> 7;
        const float* src;
        switch (m) {
            case 0: src = Wz; break;
            case 1: src = Uz; break;
            case 2: src = Wr; break;
            case 3: src = Ur; break;
            case 4: src = Wh; break;
            default: src = Uh; break;
        }
        float lo = src[i * 256 + 2 * d2];
        float hi = src[i * 256 + 2 * d2 + 1];
        Tp[m * 32768 + d2 * 256 + i] = (u32)f2bf(lo) | ((u32)f2bf(hi) << 16);
        return;
    }
    __shared__ float pl[256];
    __shared__ float s_invn;
    pl[tid] = p[tid];
    __syncthreads();
    if (tid < 64) {
        float v = pl[tid] * pl[tid] + pl[tid + 64] * pl[tid + 64] +
                  pl[tid + 128] * pl[tid + 128] + pl[tid + 192] * pl[tid + 192];
        for (int o = 32; o > 0; o >>= 1) v += __shfl_xor(v, o);
        if (tid == 0) s_invn = 1.0f / sqrtf(v);
    }
    __syncthreads();
    int wid = tid >> 6, lane = tid & 63;
    for (int it = 0; it < 4; ++it) {
        int node = blockIdx.x * 16 + wid * 4 + it;   // 5000*16 == 80000
        const float* row = x + (size_t)node * DIN + lane * 4;
        float4 u = *(const float4*)row;
        float d = u.x * pl[lane * 4 + 0] + u.y * pl[lane * 4 + 1] +
                  u.z * pl[lane * 4 + 2] + u.w * pl[lane * 4 + 3];
        u32 p0 = (u32)f2bf(u.x) | ((u32)f2bf(u.y) << 16);
        u32 p1 = (u32)f2bf(u.z) | ((u32)f2bf(u.w) << 16);
        *(uint2*)(xb16 + (size_t)node * DIN + lane * 4) = make_uint2(p0, p1);
        for (int o = 32; o > 0; o >>= 1) d += __shfl_xor(d, o);
        if (lane == 0) scores[node] = d * s_invn + mask[node];
    }
}

// ---------------- phase 1: LDS-staged coarse binning ----------------
// Pack: bits [0,17) = t*N+src, [17,25) = dstLocal (0..159), [25,32) = bucket (0..124)
__global__ __launch_bounds__(256) void k_bin(const int* ei, const float* ew,
                                             int* gcur, uint2* binned) {
    int blk = blockIdx.x;                // 0..999
    int t = blk / 250, ci = blk - t * 250;
    int ebase = ci * 2560;
    int tid = threadIdx.x;
    __shared__ u32 hist[128], sc[128], gbase[128];
    __shared__ uint2 stage[2560];
    if (tid < 128) hist[tid] = 0;
    __syncthreads();
    u32 px[10]; u32 pw[10]; u16 rk[10];
#pragma unroll
    for (int k = 0; k < 10; ++k) {
        int e = ebase + tid + k * 256;                  // < E_ exactly
        int dst = ei[t * (2 * E_) + e];
        int src = ei[t * (2 * E_) + E_ + e];
        float w = ew[t * E_ + e];
        int b = dst / BNODES;                           // 0..124
        int dl = dst - b * BNODES;                      // 0..159
        px[k] = (u32)(t * N_ + src) | ((u32)dl << 17) | ((u32)b << 25);
        pw[k] = __float_as_uint(w);
        rk[k] = (u16)atomicAdd(&hist[b], 1u);
    }
    __syncthreads();
    // inclusive scan of hist (125 live, padded to 128)
    if (tid < 128) sc[tid] = hist[tid];
    __syncthreads();
    for (int o = 1; o < 128; o <<= 1) {
        u32 v = 0;
        if (tid < 128) { v = sc[tid]; if (tid >= o) v += sc[tid - o]; }
        __syncthreads();
        if (tid < 128) sc[tid] = v;
        __syncthreads();
    }
    // reserve contiguous global runs (one atomic per bucket per block)
    if (tid < NB) gbase[tid] = (u32)atomicAdd(&gcur[t * NB + tid], (int)hist[tid]);
    // stage into bucket-sorted LDS order: slot = exclusiveStart(b) + rank
#pragma unroll
    for (int k = 0; k < 10; ++k) {
        int b = px[k] >> 25;
        u32 slot = (sc[b] - hist[b]) + rk[k];
        stage[slot] = make_uint2(px[k], pw[k]);
    }
    __syncthreads();
    // flush: consecutive slots -> consecutive global addresses within each bucket run
    for (int s = tid; s < 2560; s += 256) {
        uint2 v = stage[s];
        int b = v.x >> 25;
        u32 local = gbase[b] + ((u32)s - (sc[b] - hist[b]));
        if (local < CAP)
            binned[(size_t)(t * NB + b) * CAP + local] = v;
    }
}

// ---------------- phase 2: in-place per-bucket counting sort by (quarter, band, dl) ----
__global__ __launch_bounds__(512) void k_scatter(const int* gcur, uint2* binned, int* bandoff) {
    int bg = blockIdx.x;                 // 0..499
    int t = bg / NB;
    uint2* bucket = binned + (size_t)bg * CAP;
    int cnt = gcur[bg]; if (cnt > CAP) cnt = CAP;
    int tid = threadIdx.x;
    int tbase = t * N_;
    __shared__ u32 nhist[NBIN_PAD];
    __shared__ u32 binstart[NBIN_PAD];
    __shared__ u32 wsum[8];
    for (int i = tid; i < NBIN_PAD; i += 512) nhist[i] = 0;
    __syncthreads();
    u32 vx[11]; u32 vw[11]; u16 r_[11]; u16 bn_[11];
#pragma unroll
    for (int k = 0; k < 11; ++k) {       // 11*512 = 5632 = CAP
        int e = tid + k * 512;
        uint2 v;
        if (e < cnt) {
            v = bucket[e];
        } else {
            // synthetic pad: zero weight, reads a real row, dl spread for balance
            v = make_uint2(((u32)(e % BNODES) << 17) | (u32)(tbase + N_ - 1), 0u);
        }
        vx[k] = v.x; vw[k] = v.y;
        int dl = (v.x >> 17) & 255;
        int s = (int)(v.x & 0x1FFFFu) - tbase;          // 0..19999
        int bin = (dl / 5) * (NSB * 5) + (s >> SGRAN) * 5 + (dl % 5);   // 0..1599
        bn_[k] = (u16)bin;
        r_[k] = (u16)atomicAdd(&nhist[bin], 1u);
    }
    __syncthreads();
    // exclusive scan over 2048 bins: thread sums 4, then scan 512 thread-sums
    u32 loc1, loc2, loc3, tsum;
    {
        int b0 = tid * 4;
        u32 a = nhist[b0], b = nhist[b0 + 1], c = nhist[b0 + 2], d = nhist[b0 + 3];
        loc1 = a; loc2 = a + b; loc3 = a + b + c; tsum = a + b + c + d;
    }
    int lane = tid & 63, wv = tid >> 6;
    u32 xsc = tsum;
    for (int o = 1; o < 64; o <<= 1) { u32 yv = __shfl_up(xsc, o); if (lane >= o) xsc += yv; }
    if (lane == 63) wsum[wv] = xsc;
    __syncthreads();
    u32 wpre = 0;
    for (int wq = 0; wq < wv; ++wq) wpre += wsum[wq];
    u32 tpre = wpre + xsc - tsum;
    {
        int b0 = tid * 4;
        binstart[b0] = tpre;
        binstart[b0 + 1] = tpre + loc1;
        binstart[b0 + 2] = tpre + loc2;
        binstart[b0 + 3] = tpre + loc3;
    }
    __syncthreads();
    if (tid < 33) {
        int v = (tid < 32) ? (int)binstart[tid * (NSB * 5)] : CAP;
        bandoff[bg * BOSTRIDE + tid] = v;
    }
#pragma unroll
    for (int k = 0; k < 11; ++k) {
        u32 pos = binstart[bn_[k]] + r_[k];             // exact permutation of 0..CAP-1
        bucket[pos] = make_uint2(vx[k] & 0x1FFFFFFu, vw[k]);   // keep (dl, src)
    }
}

// ---------------- top-128 (radix select, exact jax order) + xtT build ----------------
__global__ __launch_bounds__(1024) void k_topk(const float* scores, const float* x, float* xtT) {
    int t = blockIdx.x;
    int tid = threadIdx.x;   // 0..1023
    const float* sc = scores + t * N_;
    __shared__ u32 hist[256];
    __shared__ u32 sh_dig, sh_need;
    __shared__ u64 sel[256];
    __shared__ u32 selCount;
    __shared__ u32 idxl[128];
    __shared__ float tvl[128];

    u32 kreg[20];
#pragma unroll
    for (int p = 0; p < 20; ++p) {
        int i = tid + p * 1024;
        kreg[p] = (i < N_) ? fkey(sc[i]) : 0u;
    }

    u32 pref = 0;
    u32 need = 128;
    for (int pass = 0; pass < 4; ++pass) {
        int shift = 24 - 8 * pass;
        if (tid < 256) hist[tid] = 0;
        __syncthreads();
#pragma unroll
        for (int p = 0; p < 20; ++p) {
            int i = tid + p * 1024;
            u32 k = kreg[p];
            bool ok = (i < N_) && ((pass == 0) || ((k >> (shift + 8)) == pref));
            if (ok) atomicAdd(&hist[(k >> shift) & 255u], 1u);
        }
        __syncthreads();
        if (tid < 64) {
            int l = tid;
            u32 s = hist[4 * l] + hist[4 * l + 1] + hist[4 * l + 2] + hist[4 * l + 3];
            u32 S = s;
            for (int o = 1; o < 64; o <<= 1) {
                u32 y = __shfl_down(S, o);
                if (l + o < 64) S += y;
            }
            u64 m = __ballot(S >= need);
            int L = 63 - __builtin_clzll(m);
            if (l == L) {
                u32 Snext = S - s;
                u32 r = 0;
                for (int dd = 3; dd >= 0; --dd) {
                    u32 hb = hist[4 * L + dd];
                    r += hb;
                    if (Snext + r >= need) {
                        sh_dig = (u32)(4 * L + dd);
                        sh_need = need - (Snext + r - hb);
                        break;
                    }
                }
            }
        }
        __syncthreads();
        pref = (pref << 8) | sh_dig;
        need = sh_need;
        __syncthreads();
    }
    if (tid == 0) selCount = 0;
    __syncthreads();
    u32 theta = pref;
#pragma unroll
    for (int p = 0; p < 20; ++p) {
        int i = tid + p * 1024;
        u32 k = kreg[p];
        if (i < N_ && k >= theta) {
            u32 pos = atomicAdd(&selCount, 1u);
            if (pos < 256) sel[pos] = (((u64)(k ^ 0xFFFFFFFFu)) << 32) | (u32)i;
        }
    }
    __syncthreads();
    u32 c = selCount;
    if (c > 256) c = 256;
    if (tid < 256 && (u32)tid >= c) sel[tid] = 0xFFFFFFFFFFFFFFFFull;
    __syncthreads();
    // bitonic ascending sort: key = (~fkey)<<32 | idx  -> value desc, idx asc
    for (int k2 = 2; k2 <= 256; k2 <<= 1) {
        for (int jj = k2 >> 1; jj > 0; jj >>= 1) {
            if (tid < 256) {
                int i = tid, ixj = i ^ jj;
                if (ixj > i) {
                    u64 A = sel[i], B = sel[ixj];
                    bool asc = ((i & k2) == 0);
                    bool sw = asc ? (A > B) : (A < B);
                    if (sw) { sel[i] = B; sel[ixj] = A; }
                }
            }
            __syncthreads();
        }
    }
    if (tid < 128) {
        u64 v = sel[tid];
        u32 k = ((u32)(v >> 32)) ^ 0xFFFFFFFFu;
        idxl[tid] = (u32)(v & 0xFFFFFFFFu);
        tvl[tid] = tanhf(fkeyinv(k));
    }
    __syncthreads();
    float* xt_t = xtT + t * (DIN * DOUT);
    const float* xb = x + (size_t)t * N_ * DIN;
    for (int e2 = tid; e2 < DIN * DOUT; e2 += 1024) {
        int j = e2 >> 8, d = e2 & 255;
        xt_t[e2] = xb[(size_t)idxl[j] * DIN + d] * tvl[j];
    }
}

// ---------------- fused matrix-GRU, 4-way split-K (1024 threads/column-block) --------
// One block per COLUMN j (128 blocks), 1024 threads = (row i, K-quarter qk). Each
// thread accumulates its gate partial over 32 of 128 d-pairs; quarters combine via
// 4-entry LDS reduce (bias post-reduction). All quarters redundantly compute z/r/Wn
// from the shared sums so the register-carried wv stays consistent.
// vs R8: 2x waves/block (16), 1/2 serial chain -> better latency hiding.
__global__ __launch_bounds__(1024) void k_gru(const float* xtT, const float* W0, const u32* Tp,
                                              const float* bz, const float* br, const float* bh,
                                              u16* WnT) {
    int j = blockIdx.x;           // 0..127 column
    int tid = threadIdx.x;        // 0..1023
    int i = tid & 255;            // row
    int qk = tid >> 8;            // K-quarter
    __shared__ float sxt[256], sW[256], srw[256];
    __shared__ float p1[4][256], p2[4][256];
    const u32* WzT = Tp;
    const u32* UzT = Tp + 32768;
    const u32* WrT = Tp + 65536;
    const u32* UrT = Tp + 98304;
    const u32* WhT = Tp + 131072;
    const u32* UhT = Tp + 163840;
    float wv = W0[i * 128 + j];
    float azb = bz[i * 128 + j];
    float arb = br[i * 128 + j];
    float ahb = bh[i * 128 + j];
    int d2base = qk * 32;
    for (int t = 0; t < T_; ++t) {
        __syncthreads();          // prior iteration's shared reads complete
        if (qk == 0) {
            sxt[i] = xtT[t * 32768 + j * 256 + i];
            sW[i] = wv;
        }
        __syncthreads();
        float az = 0.f, ar = 0.f;
#pragma unroll 4
        for (int dd = 0; dd < 32; ++dd) {
            int d2 = d2base + dd;
            float x0 = sxt[2 * d2], x1 = sxt[2 * d2 + 1];
            float w0 = sW[2 * d2], w1 = sW[2 * d2 + 1];
            u32 a = WzT[d2 * 256 + i], b = UzT[d2 * 256 + i];
            u32 cc = WrT[d2 * 256 + i], dv = UrT[d2 * 256 + i];
            az += blo(a) * x0 + bhi(a) * x1 + blo(b) * w0 + bhi(b) * w1;
            ar += blo(cc) * x0 + bhi(cc) * x1 + blo(dv) * w0 + bhi(dv) * w1;
        }
        p1[qk][i] = az;
        p2[qk][i] = ar;
        __syncthreads();
        float azs = p1[0][i] + p1[1][i] + p1[2][i] + p1[3][i] + azb;
        float ars = p2[0][i] + p2[1][i] + p2[2][i] + p2[3][i] + arb;
        float z = 1.0f / (1.0f + expf(-azs));
        float r = 1.0f / (1.0f + expf(-ars));
        if (qk == 0) srw[i] = r * wv;
        __syncthreads();          // srw ready; also separates p1 reuse below
        float ah = 0.f;
#pragma unroll 4
        for (int dd = 0; dd < 32; ++dd) {
            int d2 = d2base + dd;
            float x0 = sxt[2 * d2], x1 = sxt[2 * d2 + 1];
            float r0 = srw[2 * d2], r1 = srw[2 * d2 + 1];
            u32 a = WhT[d2 * 256 + i], b = UhT[d2 * 256 + i];
            ah += blo(a) * x0 + bhi(a) * x1 + blo(b) * r0 + bhi(b) * r1;
        }
        p1[qk][i] = ah;
        __syncthreads();
        float ahs = p1[0][i] + p1[1][i] + p1[2][i] + p1[3][i] + ahb;
        float hh = tanhf(ahs);
        float wn = (1.0f - z) * wv + z * hh;
        if (qk == 0) WnT[t * 32768 + j * 256 + i] = f2bf(wn);
        wv = wn;
    }
}

// ---------------- y = x_bf16 @ Wn (MFMA bf16), batched over t ----------------
__global__ __launch_bounds__(128) void k_gemm(const u16* xb16, const u16* WnT, u16* y) {
    int t = blockIdx.y;
    const u16* xb = xb16 + (size_t)t * N_ * DIN;
    const u16* Bt = WnT + t * (DIN * DOUT);
    u16* yb = y + (size_t)t * N_ * DOUT;
    int wid = threadIdx.x >> 6, lane = threadIdx.x & 63;
    int quad = lane >> 4, lm = lane & 15;
    int rowBase = blockIdx.x * 64 + wid * 32;
    f32x4 acc[2][8];
#pragma unroll
    for (int mi = 0; mi < 2; ++mi)
#pragma unroll
        for (int ni = 0; ni < 8; ++ni) acc[mi][ni] = (f32x4){0.f, 0.f, 0.f, 0.f};
    size_t aoff[2];
#pragma unroll
    for (int mi = 0; mi < 2; ++mi) {
        int r = rowBase + mi * 16 + lm;
        if (r > N_ - 1) r = N_ - 1;
        aoff[mi] = (size_t)r * DIN + quad * 8;
    }
    const u16* bbase = Bt + lm * 256 + quad * 8;
    for (int kk = 0; kk < 256; kk += 32) {
        short8 a0 = *(const short8*)(xb + aoff[0] + kk);
        short8 a1 = *(const short8*)(xb + aoff[1] + kk);
#pragma unroll
        for (int ni = 0; ni < 8; ++ni) {
            short8 b = *(const short8*)(bbase + ni * 4096 + kk);
            acc[0][ni] = __builtin_amdgcn_mfma_f32_16x16x32_bf16(a0, b, acc[0][ni], 0, 0, 0);
            acc[1][ni] = __builtin_amdgcn_mfma_f32_16x16x32_bf16(a1, b, acc[1][ni], 0, 0, 0);
        }
    }
#pragma unroll
    for (int mi = 0; mi < 2; ++mi)
#pragma unroll
        for (int ni = 0; ni < 8; ++ni)
#pragma unroll
            for (int r = 0; r < 4; ++r) {
                int row = rowBase + mi * 16 + quad * 4 + r;
                if (row < N_) yb[(size_t)row * DOUT + ni * 16 + lm] = f2bf(acc[mi][ni][r]);
            }
}

// ---------------- bucket-resident aggregation, quarter-parallel, 8-deep MLP ----------
// One block per (t, bucket): 160 dst rows in 80KB LDS f32, 2 blocks/CU, all 500
// co-resident. Quarter Q (16 lanes) owns dl in [Q*5, Q*5+5) -> exclusive LDS rows,
// no atomics, no barriers. Quarter edges are ONE contiguous run (band-major inside).
// Inner loop: 8 edges/iteration -> 8 meta + 8 y-row loads in flight per quarter
// (32/wave). Band lockstep keeps per-XCD y footprint << 4MB L2 (FETCH ~32MB floor).
__global__ __launch_bounds__(512, 4) void k_agg(const uint2* binned, const int* bandoff,
                                                const u16* y, float* out) {
    int bid = blockIdx.x;                 // 0..511 (12 dead)
    int xcd = bid & 7;
    int t = xcd >> 1;
    int bl = ((bid >> 3) << 1) + (xcd & 1);
    if (bl >= NB) return;
    int bg = t * NB + bl;
    const uint2* bucket = binned + (size_t)bg * CAP;
    const int* bo = bandoff + bg * BOSTRIDE;
    int w = threadIdx.x >> 6, lane = threadIdx.x & 63;
    int q = lane >> 4, lq = lane & 15;
    int Q = (w << 2) | q;                 // 0..31
    __shared__ float acc[BNODES][DOUT];   // 80 KB
#pragma unroll
    for (int r = 0; r < 20; ++r)
        *(float2*)&acc[w * 20 + r][2 * lane] = make_float2(0.f, 0.f);
    const u16* yq = y + lq * 8;
    int e = bo[Q];
    int eend = bo[Q + 1];
    int curdl = -1;
    float a0 = 0.f, a1 = 0.f, a2 = 0.f, a3 = 0.f, a4 = 0.f, a5 = 0.f, a6 = 0.f, a7 = 0.f;

#define PROC(mm, vv)                                                    \
    {                                                                   \
        int dl = (int)((mm.x >> 17) & 255u);                            \
        if (dl != curdl) {                                              \
            if (curdl >= 0) {                                           \
                float4* rp = (float4*)&acc[curdl][lq * 8];              \
                float4 r0 = rp[0], r1 = rp[1];                          \
                r0.x += a0; r0.y += a1; r0.z += a2; r0.w += a3;         \
                r1.x += a4; r1.y += a5; r1.z += a6; r1.w += a7;         \
                rp[0] = r0; rp[1] = r1;                                 \
            }                                                           \
            a0 = a1 = a2 = a3 = a4 = a5 = a6 = a7 = 0.f;                \
            curdl = dl;                                                 \
        }                                                               \
        float wt = __uint_as_float(mm.y);                               \
        a0 += wt * blo(vv.x); a1 += wt * bhi(vv.x);                     \
        a2 += wt * blo(vv.y); a3 += wt * bhi(vv.y);                     \
        a4 += wt * blo(vv.z); a5 += wt * bhi(vv.z);                     \
        a6 += wt * blo(vv.w); a7 += wt * bhi(vv.w);                     \
    }

    for (; e + 8 <= eend; e += 8) {
        uint2 m0 = bucket[e];
        uint2 m1 = bucket[e + 1];
        uint2 m2 = bucket[e + 2];
        uint2 m3 = bucket[e + 3];
        uint2 m4 = bucket[e + 4];
        uint2 m5 = bucket[e + 5];
        uint2 m6 = bucket[e + 6];
        uint2 m7 = bucket[e + 7];
        uint4 v0 = *(const uint4*)(yq + (size_t)(m0.x & 0x1FFFFu) * DOUT);
        uint4 v1 = *(const uint4*)(yq + (size_t)(m1.x & 0x1FFFFu) * DOUT);
        uint4 v2 = *(const uint4*)(yq + (size_t)(m2.x & 0x1FFFFu) * DOUT);
        uint4 v3 = *(const uint4*)(yq + (size_t)(m3.x & 0x1FFFFu) * DOUT);
        uint4 v4 = *(const uint4*)(yq + (size_t)(m4.x & 0x1FFFFu) * DOUT);
        uint4 v5 = *(const uint4*)(yq + (size_t)(m5.x & 0x1FFFFu) * DOUT);
        uint4 v6 = *(const uint4*)(yq + (size_t)(m6.x & 0x1FFFFu) * DOUT);
        uint4 v7 = *(const uint4*)(yq + (size_t)(m7.x & 0x1FFFFu) * DOUT);
        PROC(m0, v0)
        PROC(m1, v1)
        PROC(m2, v2)
        PROC(m3, v3)
        PROC(m4, v4)
        PROC(m5, v5)
        PROC(m6, v6)
        PROC(m7, v7)
    }
    for (; e + 4 <= eend; e += 4) {
        uint2 m0 = bucket[e];
        uint2 m1 = bucket[e + 1];
        uint2 m2 = bucket[e + 2];
        uint2 m3 = bucket[e + 3];
        uint4 v0 = *(const uint4*)(yq + (size_t)(m0.x & 0x1FFFFu) * DOUT);
        uint4 v1 = *(const uint4*)(yq + (size_t)(m1.x & 0x1FFFFu) * DOUT);
        uint4 v2 = *(const uint4*)(yq + (size_t)(m2.x & 0x1FFFFu) * DOUT);
        uint4 v3 = *(const uint4*)(yq + (size_t)(m3.x & 0x1FFFFu) * DOUT);
        PROC(m0, v0)
        PROC(m1, v1)
        PROC(m2, v2)
        PROC(m3, v3)
    }
    for (; e < eend; ++e) {
        uint2 m = bucket[e];
        uint4 v = *(const uint4*)(yq + (size_t)(m.x & 0x1FFFFu) * DOUT);
        PROC(m, v)
    }
    if (curdl >= 0) {
        float4* rp = (float4*)&acc[curdl][lq * 8];
        float4 r0 = rp[0], r1 = rp[1];
        r0.x += a0; r0.y += a1; r0.z += a2; r0.w += a3;
        r1.x += a4; r1.y += a5; r1.z += a6; r1.w += a7;
        rp[0] = r0; rp[1] = r1;
    }
#undef PROC
    // epilogue: RReLU + coalesced store of the wave's own 20 rows (same-wave order)
    int gbase = t * N_ + bl * BNODES + w * 20;
#pragma unroll
    for (int r = 0; r < 20; ++r) {
        float v0 = acc[w * 20 + r][2 * lane], v1 = acc[w * 20 + r][2 * lane + 1];
        v0 = (v0 >= 0.f) ? v0 : SLOPE * v0;
        v1 = (v1 >= 0.f) ? v1 : SLOPE * v1;
        *(float2*)(out + (size_t)(gbase + r) * DOUT + 2 * lane) = make_float2(v0, v1);
    }
}

extern "C" void kernel_launch(void* const* d_in, const int* in_sizes, int n_in,
                              void* d_out, int out_size, void* d_ws, size_t ws_size,
                              hipStream_t stream) {
    const float* x = (const float*)d_in[0];
    const int* ei = (const int*)d_in[1];
    const float* ew = (const float*)d_in[2];
    const float* mask = (const float*)d_in[3];
    const float* p = (const float*)d_in[4];
    const float* Wz = (const float*)d_in[5];
    const float* Uz = (const float*)d_in[6];
    const float* bz = (const float*)d_in[7];
    const float* Wr = (const float*)d_in[8];
    const float* Ur = (const float*)d_in[9];
    const float* br = (const float*)d_in[10];
    const float* Wh = (const float*)d_in[11];
    const float* Uh = (const float*)d_in[12];
    const float* bh = (const float*)d_in[13];
    const float* W0 = (const float*)d_in[14];
    float* out = (float*)d_out;

    char* w = (char*)d_ws;
    u16* xb16 = (u16*)w;        w += (size_t)NT * DIN * 2;        // 40,960,000
    float* scores = (float*)w;  w += 320256;                      // NT f32
    float* xtT = (float*)w;     w += 4 * 32768 * 4;               // [t][128][256] f32
    u16* WnT = (u16*)w;         w += 4 * 32768 * 2;               // [t][128][256] bf16
    u32* Tp = (u32*)w;          w += 6 * 32768 * 4;               // packed transposed weights
    u16* y = (u16*)w;           w += (size_t)NT * DOUT * 2;       // [t][N][128] bf16
    uint2* binned = (uint2*)w;  w += (size_t)NBTOT * CAP * 8;     // bucketed edges (in-place sort)
    int* gcur = (int*)w;        w += 2048;                        // 500 bucket cursors
    int* bandoff = (int*)w;     w += NBTOT * BOSTRIDE * 4;        // [bucket][33 boundaries]

    hipMemsetAsync(gcur, 0, 2048, stream);

    k_scores<<<5768, 256, 0, stream>>>(x, p, mask, scores, xb16, Wz, Uz, Wr, Ur, Wh, Uh, Tp);
    k_bin<<<1000, 256, 0, stream>>>(ei, ew, gcur, binned);
    k_scatter<<<NBTOT, 512, 0, stream>>>(gcur, binned, bandoff);
    k_topk<<<4, 1024, 0, stream>>>(scores, x, xtT);
    k_gru<<<128, 1024, 0, stream>>>(xtT, W0, Tp, bz, br, bh, WnT);
    k_gemm<<<dim3(313, 4), 128, 0, stream>>>(xb16, WnT, y);
    k_agg<<<512, 512, 0, stream>>>(binned, bandoff, y, out);
}

// Round 10
// 380.561 us; speedup vs baseline: 1.7168x; 1.0155x over previous
//
#include <hip/hip_runtime.h>

typedef unsigned short u16;
typedef unsigned int u32;
typedef unsigned long long u64;

#define T_ 4
#define N_ 20000
#define E_ 640000
#define DIN 256
#define DOUT 128
#define NT (T_*N_)          // 80000
#define TE (T_*E_)          // 2560000
#define SLOPE 0.22916666666666666f

// coarse binning geometry: 125 buckets of 160 nodes per timestep
#define NB 125
#define BNODES 160
#define CAP 5632            // mean 5120, sigma ~72 -> 14 sigma headroom
#define NBTOT (T_*NB)       // 500

// k_scatter composite sort key: (quarter = dl/5, dl%5, src band)
// -> each (quarter, dl) is ONE contiguous segment -> branchless k_agg inner loop
#define SGRAN 11
#define NSB 10              // ceil(20000 / 2048)
#define NBIN (32*5*NSB)     // 1600
#define NBIN_PAD 2048
#define BOSTRIDE 168        // 161 segment boundaries per bucket, padded

typedef __attribute__((ext_vector_type(8))) short short8;
typedef __attribute__((ext_vector_type(4))) float f32x4;

__device__ __forceinline__ float blo(u32 u) { return __uint_as_float(u << 16); }
__device__ __forceinline__ float bhi(u32 u) { return __uint_as_float(u & 0xFFFF0000u); }
__device__ __forceinline__ u16 f2bf(float f) {
    u32 u = __float_as_uint(f);
    return (u16)((u + 0x7FFFu + ((u >> 16) & 1u)) >> 16);
}
__device__ __forceinline__ u32 fkey(float f) {
    u32 u = __float_as_uint(f);
    return (u & 0x80000000u) ? ~u : (u | 0x80000000u);
}
__device__ __forceinline__ float fkeyinv(u32 k) {
    u32 u = (k & 0x80000000u) ? (k ^ 0x80000000u) : ~k;
    return __uint_as_float(u);
}

// ---------------- scores (+ fused weight transpose in blocks 5000..5767) -------------
__global__ __launch_bounds__(256) void k_scores(const float* x, const float* p, const float* mask,
                                                float* scores, u16* xb16,
                                                const float* Wz, const float* Uz, const float* Wr,
                                                const float* Ur, const float* Wh, const float* Uh,
                                                u32* Tp) {
    int tid = threadIdx.x;
    if (blockIdx.x >= 5000) {
        // transpose+pack the 6 GRU weight matrices (f32 -> bf16 pairs)
        int bid = blockIdx.x - 5000;      // 0..767
        int m = bid >> 7, b = bid & 127;
        int idx = b * 256 + tid;          // 0..32767
        int d2 = idx & 127, i = idx >> 7;
        const float* src;
        switch (m) {
            case 0: src = Wz; break;
            case 1: src = Uz; break;
            case 2: src = Wr; break;
            case 3: src = Ur; break;
            case 4: src = Wh; break;
            default: src = Uh; break;
        }
        float lo = src[i * 256 + 2 * d2];
        float hi = src[i * 256 + 2 * d2 + 1];
        Tp[m * 32768 + d2 * 256 + i] = (u32)f2bf(lo) | ((u32)f2bf(hi) << 16);
        return;
    }
    __shared__ float pl[256];
    __shared__ float s_invn;
    pl[tid] = p[tid];
    __syncthreads();
    if (tid < 64) {
        float v = pl[tid] * pl[tid] + pl[tid + 64] * pl[tid + 64] +
                  pl[tid + 128] * pl[tid + 128] + pl[tid + 192] * pl[tid + 192];
        for (int o = 32; o > 0; o >>= 1) v += __shfl_xor(v, o);
        if (tid == 0) s_invn = 1.0f / sqrtf(v);
    }
    __syncthreads();
    int wid = tid >> 6, lane = tid & 63;
    for (int it = 0; it < 4; ++it) {
        int node = blockIdx.x * 16 + wid * 4 + it;   // 5000*16 == 80000
        const float* row = x + (size_t)node * DIN + lane * 4;
        float4 u = *(const float4*)row;
        float d = u.x * pl[lane * 4 + 0] + u.y * pl[lane * 4 + 1] +
                  u.z * pl[lane * 4 + 2] + u.w * pl[lane * 4 + 3];
        u32 p0 = (u32)f2bf(u.x) | ((u32)f2bf(u.y) << 16);
        u32 p1 = (u32)f2bf(u.z) | ((u32)f2bf(u.w) << 16);
        *(uint2*)(xb16 + (size_t)node * DIN + lane * 4) = make_uint2(p0, p1);
        for (int o = 32; o > 0; o >>= 1) d += __shfl_xor(d, o);
        if (lane == 0) scores[node] = d * s_invn + mask[node];
    }
}

// ---------------- phase 1: LDS-staged coarse binning ----------------
// Pack: bits [0,17) = t*N+src, [17,25) = dstLocal (0..159), [25,32) = bucket (0..124)
__global__ __launch_bounds__(256) void k_bin(const int* ei, const float* ew,
                                             int* gcur, uint2* binned) {
    int blk = blockIdx.x;                // 0..999
    int t = blk / 250, ci = blk - t * 250;
    int ebase = ci * 2560;
    int tid = threadIdx.x;
    __shared__ u32 hist[128], sc[128], gbase[128];
    __shared__ uint2 stage[2560];
    if (tid < 128) hist[tid] = 0;
    __syncthreads();
    u32 px[10]; u32 pw[10]; u16 rk[10];
#pragma unroll
    for (int k = 0; k < 10; ++k) {
        int e = ebase + tid + k * 256;                  // < E_ exactly
        int dst = ei[t * (2 * E_) + e];
        int src = ei[t * (2 * E_) + E_ + e];
        float w = ew[t * E_ + e];
        int b = dst / BNODES;                           // 0..124
        int dl = dst - b * BNODES;                      // 0..159
        px[k] = (u32)(t * N_ + src) | ((u32)dl << 17) | ((u32)b << 25);
        pw[k] = __float_as_uint(w);
        rk[k] = (u16)atomicAdd(&hist[b], 1u);
    }
    __syncthreads();
    // inclusive scan of hist (125 live, padded to 128)
    if (tid < 128) sc[tid] = hist[tid];
    __syncthreads();
    for (int o = 1; o < 128; o <<= 1) {
        u32 v = 0;
        if (tid < 128) { v = sc[tid]; if (tid >= o) v += sc[tid - o]; }
        __syncthreads();
        if (tid < 128) sc[tid] = v;
        __syncthreads();
    }
    // reserve contiguous global runs (one atomic per bucket per block)
    if (tid < NB) gbase[tid] = (u32)atomicAdd(&gcur[t * NB + tid], (int)hist[tid]);
    // stage into bucket-sorted LDS order: slot = exclusiveStart(b) + rank
#pragma unroll
    for (int k = 0; k < 10; ++k) {
        int b = px[k] >> 25;
        u32 slot = (sc[b] - hist[b]) + rk[k];
        stage[slot] = make_uint2(px[k], pw[k]);
    }
    __syncthreads();
    // flush: consecutive slots -> consecutive global addresses within each bucket run
    for (int s = tid; s < 2560; s += 256) {
        uint2 v = stage[s];
        int b = v.x >> 25;
        u32 local = gbase[b] + ((u32)s - (sc[b] - hist[b]));
        if (local < CAP)
            binned[(size_t)(t * NB + b) * CAP + local] = v;
    }
}

// ---------------- phase 2: per-bucket counting sort by (quarter, dl, band) -----------
// + fused top-128 (blocks 500..503): topk only needs 4 CUs; running it standalone
// serializes ~tens of us. Fused, it hides under the 500 scatter blocks.
__global__ __launch_bounds__(512) void k_scatter(const int* gcur, uint2* binned, int* bandoff,
                                                 const float* scores, const float* x, float* xtT) {
    int bg = blockIdx.x;
    int tid = threadIdx.x;
    if (bg >= NBTOT) {
        // ---- top-128 radix select (exact jax order) + xtT build, 512 threads ----
        int t = bg - NBTOT;
        const float* sc = scores + t * N_;
        __shared__ u32 hist[256];
        __shared__ u32 sh_dig, sh_need;
        __shared__ u64 sel[256];
        __shared__ u32 selCount;
        __shared__ u32 idxl[128];
        __shared__ float tvl[128];
        u32 kreg[40];
#pragma unroll
        for (int p = 0; p < 40; ++p) {
            int i = tid + p * 512;
            kreg[p] = (i < N_) ? fkey(sc[i]) : 0u;
        }
        u32 pref = 0;
        u32 need = 128;
        for (int pass = 0; pass < 4; ++pass) {
            int shift = 24 - 8 * pass;
            if (tid < 256) hist[tid] = 0;
            __syncthreads();
#pragma unroll
            for (int p = 0; p < 40; ++p) {
                int i = tid + p * 512;
                u32 k = kreg[p];
                bool ok = (i < N_) && ((pass == 0) || ((k >> (shift + 8)) == pref));
                if (ok) atomicAdd(&hist[(k >> shift) & 255u], 1u);
            }
            __syncthreads();
            if (tid < 64) {
                int l = tid;
                u32 s = hist[4 * l] + hist[4 * l + 1] + hist[4 * l + 2] + hist[4 * l + 3];
                u32 S = s;
                for (int o = 1; o < 64; o <<= 1) {
                    u32 y = __shfl_down(S, o);
                    if (l + o < 64) S += y;
                }
                u64 m = __ballot(S >= need);
                int L = 63 - __builtin_clzll(m);
                if (l == L) {
                    u32 Snext = S - s;
                    u32 r = 0;
                    for (int dd = 3; dd >= 0; --dd) {
                        u32 hb = hist[4 * L + dd];
                        r += hb;
                        if (Snext + r >= need) {
                            sh_dig = (u32)(4 * L + dd);
                            sh_need = need - (Snext + r - hb);
                            break;
                        }
                    }
                }
            }
            __syncthreads();
            pref = (pref << 8) | sh_dig;
            need = sh_need;
            __syncthreads();
        }
        if (tid == 0) selCount = 0;
        __syncthreads();
        u32 theta = pref;
#pragma unroll
        for (int p = 0; p < 40; ++p) {
            int i = tid + p * 512;
            u32 k = kreg[p];
            if (i < N_ && k >= theta) {
                u32 pos = atomicAdd(&selCount, 1u);
                if (pos < 256) sel[pos] = (((u64)(k ^ 0xFFFFFFFFu)) << 32) | (u32)i;
            }
        }
        __syncthreads();
        u32 c = selCount;
        if (c > 256) c = 256;
        if (tid < 256 && (u32)tid >= c) sel[tid] = 0xFFFFFFFFFFFFFFFFull;
        __syncthreads();
        // bitonic ascending sort: key = (~fkey)<<32 | idx -> value desc, idx asc
        for (int k2 = 2; k2 <= 256; k2 <<= 1) {
            for (int jj = k2 >> 1; jj > 0; jj >>= 1) {
                if (tid < 256) {
                    int i = tid, ixj = i ^ jj;
                    if (ixj > i) {
                        u64 A = sel[i], B = sel[ixj];
                        bool asc = ((i & k2) == 0);
                        bool sw = asc ? (A > B) : (A < B);
                        if (sw) { sel[i] = B; sel[ixj] = A; }
                    }
                }
                __syncthreads();
            }
        }
        if (tid < 128) {
            u64 v = sel[tid];
            u32 k = ((u32)(v >> 32)) ^ 0xFFFFFFFFu;
            idxl[tid] = (u32)(v & 0xFFFFFFFFu);
            tvl[tid] = tanhf(fkeyinv(k));
        }
        __syncthreads();
        float* xt_t = xtT + t * (DIN * DOUT);
        const float* xb = x + (size_t)t * N_ * DIN;
        for (int e2 = tid; e2 < DIN * DOUT; e2 += 512) {
            int j = e2 >> 8, d = e2 & 255;
            xt_t[e2] = xb[(size_t)idxl[j] * DIN + d] * tvl[j];
        }
        return;
    }
    // ---- counting sort path ----
    int t = bg / NB;
    uint2* bucket = binned + (size_t)bg * CAP;
    int cnt = gcur[bg]; if (cnt > CAP) cnt = CAP;
    int tbase = t * N_;
    __shared__ u32 nhist[NBIN_PAD];
    __shared__ u32 binstart[NBIN_PAD];
    __shared__ u32 wsum[8];
    for (int i = tid; i < NBIN_PAD; i += 512) nhist[i] = 0;
    __syncthreads();
    u32 vx[11]; u32 vw[11]; u16 r_[11]; u16 bn_[11];
#pragma unroll
    for (int k = 0; k < 11; ++k) {       // 11*512 = 5632 = CAP
        int e = tid + k * 512;
        uint2 v;
        if (e < cnt) {
            v = bucket[e];
        } else {
            // synthetic pad: zero weight, reads a real row, dl spread for balance
            v = make_uint2(((u32)(e % BNODES) << 17) | (u32)(tbase + N_ - 1), 0u);
        }
        vx[k] = v.x; vw[k] = v.y;
        int dl = (v.x >> 17) & 255;
        int s = (int)(v.x & 0x1FFFFu) - tbase;          // 0..19999
        // key (quarter, dl-within-quarter, band): segment per (Q, dl)
        int bin = (dl / 5) * (5 * NSB) + (dl % 5) * NSB + (s >> SGRAN);   // 0..1599
        bn_[k] = (u16)bin;
        r_[k] = (u16)atomicAdd(&nhist[bin], 1u);
    }
    __syncthreads();
    // exclusive scan over 2048 bins: thread sums 4, then scan 512 thread-sums
    u32 loc1, loc2, loc3, tsum;
    {
        int b0 = tid * 4;
        u32 a = nhist[b0], b = nhist[b0 + 1], c = nhist[b0 + 2], d = nhist[b0 + 3];
        loc1 = a; loc2 = a + b; loc3 = a + b + c; tsum = a + b + c + d;
    }
    int lane = tid & 63, wv = tid >> 6;
    u32 xsc = tsum;
    for (int o = 1; o < 64; o <<= 1) { u32 yv = __shfl_up(xsc, o); if (lane >= o) xsc += yv; }
    if (lane == 63) wsum[wv] = xsc;
    __syncthreads();
    u32 wpre = 0;
    for (int wq = 0; wq < wv; ++wq) wpre += wsum[wq];
    u32 tpre = wpre + xsc - tsum;
    {
        int b0 = tid * 4;
        binstart[b0] = tpre;
        binstart[b0 + 1] = tpre + loc1;
        binstart[b0 + 2] = tpre + loc2;
        binstart[b0 + 3] = tpre + loc3;
    }
    __syncthreads();
    // 161 segment boundaries: boundary i (= Q*5 + d) starts at bin i*NSB
    if (tid < 161) {
        int v = (tid < 160) ? (int)binstart[tid * NSB] : CAP;
        bandoff[bg * BOSTRIDE + tid] = v;
    }
#pragma unroll
    for (int k = 0; k < 11; ++k) {
        u32 pos = binstart[bn_[k]] + r_[k];             // exact permutation of 0..CAP-1
        bucket[pos] = make_uint2(vx[k] & 0x1FFFFFFu, vw[k]);   // keep (dl, src)
    }
}

// ---------------- fused matrix-GRU, 4-way split-K (1024 threads/column-block) --------
__global__ __launch_bounds__(1024) void k_gru(const float* xtT, const float* W0, const u32* Tp,
                                              const float* bz, const float* br, const float* bh,
                                              u16* WnT) {
    int j = blockIdx.x;           // 0..127 column
    int tid = threadIdx.x;        // 0..1023
    int i = tid & 255;            // row
    int qk = tid >> 8;            // K-quarter
    __shared__ float sxt[256], sW[256], srw[256];
    __shared__ float p1[4][256], p2[4][256];
    const u32* WzT = Tp;
    const u32* UzT = Tp + 32768;
    const u32* WrT = Tp + 65536;
    const u32* UrT = Tp + 98304;
    const u32* WhT = Tp + 131072;
    const u32* UhT = Tp + 163840;
    float wv = W0[i * 128 + j];
    float azb = bz[i * 128 + j];
    float arb = br[i * 128 + j];
    float ahb = bh[i * 128 + j];
    int d2base = qk * 32;
    for (int t = 0; t < T_; ++t) {
        __syncthreads();          // prior iteration's shared reads complete
        if (qk == 0) {
            sxt[i] = xtT[t * 32768 + j * 256 + i];
            sW[i] = wv;
        }
        __syncthreads();
        float az = 0.f, ar = 0.f;
#pragma unroll 4
        for (int dd = 0; dd < 32; ++dd) {
            int d2 = d2base + dd;
            float x0 = sxt[2 * d2], x1 = sxt[2 * d2 + 1];
            float w0 = sW[2 * d2], w1 = sW[2 * d2 + 1];
            u32 a = WzT[d2 * 256 + i], b = UzT[d2 * 256 + i];
            u32 cc = WrT[d2 * 256 + i], dv = UrT[d2 * 256 + i];
            az += blo(a) * x0 + bhi(a) * x1 + blo(b) * w0 + bhi(b) * w1;
            ar += blo(cc) * x0 + bhi(cc) * x1 + blo(dv) * w0 + bhi(dv) * w1;
        }
        p1[qk][i] = az;
        p2[qk][i] = ar;
        __syncthreads();
        float azs = p1[0][i] + p1[1][i] + p1[2][i] + p1[3][i] + azb;
        float ars = p2[0][i] + p2[1][i] + p2[2][i] + p2[3][i] + arb;
        float z = 1.0f / (1.0f + expf(-azs));
        float r = 1.0f / (1.0f + expf(-ars));
        if (qk == 0) srw[i] = r * wv;
        __syncthreads();          // srw ready; also separates p1 reuse below
        float ah = 0.f;
#pragma unroll 4
        for (int dd = 0; dd < 32; ++dd) {
            int d2 = d2base + dd;
            float x0 = sxt[2 * d2], x1 = sxt[2 * d2 + 1];
            float r0 = srw[2 * d2], r1 = srw[2 * d2 + 1];
            u32 a = WhT[d2 * 256 + i], b = UhT[d2 * 256 + i];
            ah += blo(a) * x0 + bhi(a) * x1 + blo(b) * r0 + bhi(b) * r1;
        }
        p1[qk][i] = ah;
        __syncthreads();
        float ahs = p1[0][i] + p1[1][i] + p1[2][i] + p1[3][i] + ahb;
        float hh = tanhf(ahs);
        float wn = (1.0f - z) * wv + z * hh;
        if (qk == 0) WnT[t * 32768 + j * 256 + i] = f2bf(wn);
        wv = wn;
    }
}

// ---------------- y = x_bf16 @ Wn (MFMA bf16), batched over t ----------------
__global__ __launch_bounds__(128) void k_gemm(const u16* xb16, const u16* WnT, u16* y) {
    int t = blockIdx.y;
    const u16* xb = xb16 + (size_t)t * N_ * DIN;
    const u16* Bt = WnT + t * (DIN * DOUT);
    u16* yb = y + (size_t)t * N_ * DOUT;
    int wid = threadIdx.x >> 6, lane = threadIdx.x & 63;
    int quad = lane >> 4, lm = lane & 15;
    int rowBase = blockIdx.x * 64 + wid * 32;
    f32x4 acc[2][8];
#pragma unroll
    for (int mi = 0; mi < 2; ++mi)
#pragma unroll
        for (int ni = 0; ni < 8; ++ni) acc[mi][ni] = (f32x4){0.f, 0.f, 0.f, 0.f};
    size_t aoff[2];
#pragma unroll
    for (int mi = 0; mi < 2; ++mi) {
        int r = rowBase + mi * 16 + lm;
        if (r > N_ - 1) r = N_ - 1;
        aoff[mi] = (size_t)r * DIN + quad * 8;
    }
    const u16* bbase = Bt + lm * 256 + quad * 8;
    for (int kk = 0; kk < 256; kk += 32) {
        short8 a0 = *(const short8*)(xb + aoff[0] + kk);
        short8 a1 = *(const short8*)(xb + aoff[1] + kk);
#pragma unroll
        for (int ni = 0; ni < 8; ++ni) {
            short8 b = *(const short8*)(bbase + ni * 4096 + kk);
            acc[0][ni] = __builtin_amdgcn_mfma_f32_16x16x32_bf16(a0, b, acc[0][ni], 0, 0, 0);
            acc[1][ni] = __builtin_amdgcn_mfma_f32_16x16x32_bf16(a1, b, acc[1][ni], 0, 0, 0);
        }
    }
#pragma unroll
    for (int mi = 0; mi < 2; ++mi)
#pragma unroll
        for (int ni = 0; ni < 8; ++ni)
#pragma unroll
            for (int r = 0; r < 4; ++r) {
                int row = rowBase + mi * 16 + quad * 4 + r;
                if (row < N_) yb[(size_t)row * DOUT + ni * 16 + lm] = f2bf(acc[mi][ni][r]);
            }
}

// ---------------- bucket-resident aggregation: branchless per-dl segments ------------
// One block per (t, bucket): 160 dst rows in 80KB LDS f32, 2 blocks/CU. Quarter Q
// (16 lanes) owns dl in [Q*5, Q*5+5); each (Q, dl) is ONE contiguous segment
// (band-major inside) -> inner loop is pure unpack+FMA (8-deep MLP), with exactly
// one unconditional LDS store per dl (no flush branch, no zero-init: every row is
// written exactly once). Band sweep repeats 5x per quarter; drift keeps per-XCD
// y footprint ~2-4 bands (1-2MB) < 4MB L2.
__global__ __launch_bounds__(512, 4) void k_agg(const uint2* binned, const int* bandoff,
                                                const u16* y, float* out) {
    int bid = blockIdx.x;                 // 0..511 (12 dead)
    int xcd = bid & 7;
    int t = xcd >> 1;
    int bl = ((bid >> 3) << 1) + (xcd & 1);
    if (bl >= NB) return;
    int bg = t * NB + bl;
    const uint2* bucket = binned + (size_t)bg * CAP;
    const int* bo = bandoff + bg * BOSTRIDE;
    int w = threadIdx.x >> 6, lane = threadIdx.x & 63;
    int q = lane >> 4, lq = lane & 15;
    int Q = (w << 2) | q;                 // 0..31
    __shared__ float acc[BNODES][DOUT];   // 80 KB
    const u16* yq = y + lq * 8;

#define FMA8(mm, vv)                                                    \
    {                                                                   \
        float wt = __uint_as_float(mm.y);                               \
        a0 += wt * blo(vv.x); a1 += wt * bhi(vv.x);                     \
        a2 += wt * blo(vv.y); a3 += wt * bhi(vv.y);                     \
        a4 += wt * blo(vv.z); a5 += wt * bhi(vv.z);                     \
        a6 += wt * blo(vv.w); a7 += wt * bhi(vv.w);                     \
    }

#pragma unroll
    for (int d = 0; d < 5; ++d) {
        int e = bo[Q * 5 + d];
        int eend = bo[Q * 5 + d + 1];     // d==4: next quarter's start (contiguous)
        float a0 = 0.f, a1 = 0.f, a2 = 0.f, a3 = 0.f;
        float a4 = 0.f, a5 = 0.f, a6 = 0.f, a7 = 0.f;
        for (; e + 8 <= eend; e += 8) {
            uint2 m0 = bucket[e];
            uint2 m1 = bucket[e + 1];
            uint2 m2 = bucket[e + 2];
            uint2 m3 = bucket[e + 3];
            uint2 m4 = bucket[e + 4];
            uint2 m5 = bucket[e + 5];
            uint2 m6 = bucket[e + 6];
            uint2 m7 = bucket[e + 7];
            uint4 v0 = *(const uint4*)(yq + (size_t)(m0.x & 0x1FFFFu) * DOUT);
            uint4 v1 = *(const uint4*)(yq + (size_t)(m1.x & 0x1FFFFu) * DOUT);
            uint4 v2 = *(const uint4*)(yq + (size_t)(m2.x & 0x1FFFFu) * DOUT);
            uint4 v3 = *(const uint4*)(yq + (size_t)(m3.x & 0x1FFFFu) * DOUT);
            uint4 v4 = *(const uint4*)(yq + (size_t)(m4.x & 0x1FFFFu) * DOUT);
            uint4 v5 = *(const uint4*)(yq + (size_t)(m5.x & 0x1FFFFu) * DOUT);
            uint4 v6 = *(const uint4*)(yq + (size_t)(m6.x & 0x1FFFFu) * DOUT);
            uint4 v7 = *(const uint4*)(yq + (size_t)(m7.x & 0x1FFFFu) * DOUT);
            FMA8(m0, v0)
            FMA8(m1, v1)
            FMA8(m2, v2)
            FMA8(m3, v3)
            FMA8(m4, v4)
            FMA8(m5, v5)
            FMA8(m6, v6)
            FMA8(m7, v7)
        }
        for (; e < eend; ++e) {
            uint2 m = bucket[e];
            uint4 v = *(const uint4*)(yq + (size_t)(m.x & 0x1FFFFu) * DOUT);
            FMA8(m, v)
        }
        // each (Q, d) row written exactly once -> plain store, no zero-init needed
        float4* rp = (float4*)&acc[Q * 5 + d][lq * 8];
        rp[0] = make_float4(a0, a1, a2, a3);
        rp[1] = make_float4(a4, a5, a6, a7);
    }
#undef FMA8
    // epilogue: RReLU + coalesced store of the wave's own 20 rows (same-wave order)
    int gbase = t * N_ + bl * BNODES + w * 20;
#pragma unroll
    for (int r = 0; r < 20; ++r) {
        float v0 = acc[w * 20 + r][2 * lane], v1 = acc[w * 20 + r][2 * lane + 1];
        v0 = (v0 >= 0.f) ? v0 : SLOPE * v0;
        v1 = (v1 >= 0.f) ? v1 : SLOPE * v1;
        *(float2*)(out + (size_t)(gbase + r) * DOUT + 2 * lane) = make_float2(v0, v1);
    }
}

extern "C" void kernel_launch(void* const* d_in, const int* in_sizes, int n_in,
                              void* d_out, int out_size, void* d_ws, size_t ws_size,
                              hipStream_t stream) {
    const float* x = (const float*)d_in[0];
    const int* ei = (const int*)d_in[1];
    const float* ew = (const float*)d_in[2];
    const float* mask = (const float*)d_in[3];
    const float* p = (const float*)d_in[4];
    const float* Wz = (const float*)d_in[5];
    const float* Uz = (const float*)d_in[6];
    const float* bz = (const float*)d_in[7];
    const float* Wr = (const float*)d_in[8];
    const float* Ur = (const float*)d_in[9];
    const float* br = (const float*)d_in[10];
    const float* Wh = (const float*)d_in[11];
    const float* Uh = (const float*)d_in[12];
    const float* bh = (const float*)d_in[13];
    const float* W0 = (const float*)d_in[14];
    float* out = (float*)d_out;

    char* w = (char*)d_ws;
    u16* xb16 = (u16*)w;        w += (size_t)NT * DIN * 2;        // 40,960,000
    float* scores = (float*)w;  w += 320256;                      // NT f32
    float* xtT = (float*)w;     w += 4 * 32768 * 4;               // [t][128][256] f32
    u16* WnT = (u16*)w;         w += 4 * 32768 * 2;               // [t][128][256] bf16
    u32* Tp = (u32*)w;          w += 6 * 32768 * 4;               // packed transposed weights
    u16* y = (u16*)w;           w += (size_t)NT * DOUT * 2;       // [t][N][128] bf16
    uint2* binned = (uint2*)w;  w += (size_t)NBTOT * CAP * 8;     // bucketed edges (in-place sort)
    int* gcur = (int*)w;        w += 2048;                        // 500 bucket cursors
    int* bandoff = (int*)w;     w += NBTOT * BOSTRIDE * 4;        // [bucket][161 boundaries]

    hipMemsetAsync(gcur, 0, 2048, stream);

    k_scores<<<5768, 256, 0, stream>>>(x, p, mask, scores, xb16, Wz, Uz, Wr, Ur, Wh, Uh, Tp);
    k_bin<<<1000, 256, 0, stream>>>(ei, ew, gcur, binned);
    k_scatter<<<NBTOT + 4, 512, 0, stream>>>(gcur, binned, bandoff, scores, x, xtT);
    k_gru<<<128, 1024, 0, stream>>>(xtT, W0, Tp, bz, br, bh, WnT);
    k_gemm<<<dim3(313, 4), 128, 0, stream>>>(xb16, WnT, y);
    k_agg<<<512, 512, 0, stream>>>(binned, bandoff, y, out);
}